// Round 15
// baseline (303.908 us; speedup 1.0000x reference)
//
#include <hip/hip_runtime.h>
#include <cstdint>
#include <cstddef>

typedef _Float16 half4v __attribute__((ext_vector_type(4)));
typedef _Float16 half8v __attribute__((ext_vector_type(8)));
typedef float    f32x4  __attribute__((ext_vector_type(4)));

#define N_PTS   262144
#define CDIM    64
#define KCODES  512
#define TAUA    5e-3f          // acc-units; true-dist gap = 2*acc gap -> 1e-2 (r10 proven)
#define FLAG_CAP 65536u

// output offsets (floats): out, diff, embedding_ind, new_embedding, new_cluster_size, new_embedding_avg
#define OFF_DIFF 16777216u
#define OFF_IND  16777217u
#define OFF_EMB  17039361u
#define OFF_CSZ  17072129u
#define OFF_AVG  17072641u

// ---------------------------------------------------------------- main: MFMA f16x2-split distances + argmin
// acc = ee/2 + (-x)*e  ->  dist = 2*acc + xx  (argmin equivalent in acc units)
// r10-proven inner loop & numerics; 16-wave WG for 4 waves/SIMD.
// __launch_bounds__(1024, 1): arg2 is empirically CUDA-style min-BLOCKS/CU on this toolchain
// (r6: (512,4) -> 64-VGPR cap = 32 waves/CU). 1 block/CU = 16 waves = 4/SIMD -> VGPR cap 128,
// matching r10's measured allocation. r13 (no arg2) let the compiler target 2 blocks -> 64 VGPR -> spills.
__global__ __launch_bounds__(1024, 1) void k_main(
    const float* __restrict__ in, const float* __restrict__ emb,
    float* __restrict__ out,
    int* __restrict__ ind_buf, float* __restrict__ diff_acc,
    unsigned* __restrict__ nflag, int* __restrict__ flaglist)
{
    // LDS: B_hi [64KiB] | B_lo [64KiB] | ee2 [2KiB]   (swizzled: byte ^= (col&7)<<4)
    __shared__ __align__(16) char bsm[133120];
    float* ee2_lds = (float*)(bsm + 131072);
    const int tid = threadIdx.x;

    // ---- stage codebook: fp32 -> f16 hi/lo by wave-plane; ee2 computed by hi-plane ----
    {
        const int col = tid & 511;           // 512 cols x 2 planes
        const int pl  = tid >> 9;            // 0 = hi (+ee2), 1 = lo   (wave-uniform)
        const int xr  = (col & 7) << 4;
        float s = 0.f;
        #pragma unroll
        for (int c0 = 0; c0 < CDIM; c0 += 4) {
            float v[4];
            #pragma unroll
            for (int i = 0; i < 4; ++i) v[i] = emb[(c0 + i)*KCODES + col];
            half4v h;
            if (pl == 0) {
                #pragma unroll
                for (int i = 0; i < 4; ++i) {
                    s = fmaf(v[i], v[i], s);
                    h[i] = (_Float16)v[i];
                }
            } else {
                #pragma unroll
                for (int i = 0; i < 4; ++i) {
                    const _Float16 hh = (_Float16)v[i];
                    h[i] = (_Float16)(v[i] - (float)hh);
                }
            }
            *(half4v*)(bsm + (pl << 16) + col*128 + ((c0*2) ^ xr)) = h;
        }
        if (pl == 0) ee2_lds[col] = 0.5f * s;
    }
    __syncthreads();

    const int w  = tid >> 6, l = tid & 63;   // 16 waves, 64 points each
    const int g  = l >> 4,  lc = l & 15;

    const int pbase = (blockIdx.x << 10) + (w << 6);
    const int b     = pbase >> 12;
    const float* inb = in + ((size_t)b << 18) + ((pbase & 4095) + lc);

    // ---- A fragments: negated x, exact f16 split; xx accumulated on the fly ----
    half8v ah[4][2], al[4][2];
    float xs = 0.f;
    #pragma unroll
    for (int t = 0; t < 4; ++t)
        #pragma unroll
        for (int s = 0; s < 2; ++s)
            #pragma unroll
            for (int j = 0; j < 8; ++j) {
                const int c = s*32 + g*8 + j;
                const float x = inb[(size_t)c*4096 + t*16];
                xs = fmaf(x, x, xs);
                const float xf = -x;
                const _Float16 hh = (_Float16)xf;
                ah[t][s][j] = hh;
                al[t][s][j] = (_Float16)(xf - (float)hh);
            }

    float d1[4][4], d2[4][4]; int k1[4][4];
    #pragma unroll
    for (int t = 0; t < 4; ++t)
        #pragma unroll
        for (int rr = 0; rr < 4; ++rr) { d1[t][rr] = 3.4e38f; d2[t][rr] = 3.4e38f; k1[t][rr] = 0; }

    for (int ct = 0; ct < 32; ++ct) {
        const int col  = (ct << 4) + lc;
        const float sd = ee2_lds[col];
        const int rb   = col*128 + ((g*16) ^ ((col & 7) << 4));
        half8v bh0 = *(const half8v*)(bsm + rb);
        half8v bh1 = *(const half8v*)(bsm + (rb ^ 64));
        half8v bl0 = *(const half8v*)(bsm + 65536 + rb);
        half8v bl1 = *(const half8v*)(bsm + 65536 + (rb ^ 64));

        #pragma unroll
        for (int t = 0; t < 4; ++t) {
            // two independent 3-deep chains (K-halves s=0 / s=1)
            f32x4 acc0 = {sd, sd, sd, sd};
            f32x4 acc1 = {0.f, 0.f, 0.f, 0.f};
            acc0 = __builtin_amdgcn_mfma_f32_16x16x32_f16(al[t][0], bh0, acc0, 0, 0, 0);
            acc1 = __builtin_amdgcn_mfma_f32_16x16x32_f16(al[t][1], bh1, acc1, 0, 0, 0);
            acc0 = __builtin_amdgcn_mfma_f32_16x16x32_f16(ah[t][0], bl0, acc0, 0, 0, 0);
            acc1 = __builtin_amdgcn_mfma_f32_16x16x32_f16(ah[t][1], bl1, acc1, 0, 0, 0);
            acc0 = __builtin_amdgcn_mfma_f32_16x16x32_f16(ah[t][0], bh0, acc0, 0, 0, 0);
            acc1 = __builtin_amdgcn_mfma_f32_16x16x32_f16(ah[t][1], bh1, acc1, 0, 0, 0);
            #pragma unroll
            for (int rr = 0; rr < 4; ++rr) {
                const float d = acc0[rr] + acc1[rr];
                const bool cc = d < d1[t][rr];
                d2[t][rr] = fminf(d2[t][rr], fmaxf(d, d1[t][rr]));
                d1[t][rr] = fminf(d1[t][rr], d);
                k1[t][rr] = cc ? col : k1[t][rr];
            }
        }
    }

    // ---- cross-lane best-2 merge over the 16 col-lanes ----
    #pragma unroll
    for (int m = 1; m <= 8; m <<= 1) {
        #pragma unroll
        for (int t = 0; t < 4; ++t)
            #pragma unroll
            for (int rr = 0; rr < 4; ++rr) {
                const float od1 = __shfl_xor(d1[t][rr], m);
                const int   ok1 = __shfl_xor(k1[t][rr], m);
                const float od2 = __shfl_xor(d2[t][rr], m);
                const float nd2 = fminf(fmaxf(d1[t][rr], od1), fminf(d2[t][rr], od2));
                const bool take = (od1 < d1[t][rr]) || (od1 == d1[t][rr] && ok1 < k1[t][rr]);
                d1[t][rr] = take ? od1 : d1[t][rr];
                k1[t][rr] = take ? ok1 : k1[t][rr];
                d2[t][rr] = nd2;
            }
    }

    // ---- outputs: indices, near-tie flags, diff partial ----
    float ds = 0.f;
    if (lc == 0) {
        #pragma unroll
        for (int t = 0; t < 4; ++t) {
            const int nb = pbase + t*16 + (g << 2);
            int4 iv = make_int4(k1[t][0], k1[t][1], k1[t][2], k1[t][3]);
            *(int4*)(ind_buf + nb) = iv;
            #pragma unroll
            for (int rr = 0; rr < 4; ++rr) {
                out[OFF_IND + nb + rr] = (float)k1[t][rr];
                ds += d1[t][rr];
                if (d2[t][rr] - d1[t][rr] < TAUA) {
                    unsigned ix = atomicAdd(nflag, 1u);
                    if (ix < FLAG_CAP) flaglist[ix] = nb + rr;
                }
            }
        }
    }
    #pragma unroll
    for (int m = 1; m < 64; m <<= 1) {
        ds += __shfl_xor(ds, m);
        xs += __shfl_xor(xs, m);
    }
    if (l == 0) atomicAdd(diff_acc, 2.f*ds + xs);
}

// ---------------------------------------------------------------- f64 exact re-scan for near-ties
__global__ void k_refine(const float* __restrict__ in, const float* __restrict__ emb,
                         const unsigned* __restrict__ nflag, const int* __restrict__ flaglist,
                         int* __restrict__ ind_buf, float* __restrict__ out)
{
    const int gtid = blockIdx.x*blockDim.x + threadIdx.x;
    const int wid  = gtid >> 6;
    const int lane = threadIdx.x & 63;
    const int nw   = (gridDim.x * blockDim.x) >> 6;
    unsigned nf = *nflag; if (nf > FLAG_CAP) nf = FLAG_CAP;
    for (unsigned f = wid; f < nf; f += nw) {
        const int n = flaglist[f];
        const int b = n >> 12, hw = n & 4095;
        const float* xb = in + ((size_t)b << 18) + hw;
        const float* er = emb + lane*8;
        double dd[8] = {0,0,0,0,0,0,0,0};
        for (int c = 0; c < CDIM; ++c) {
            const double xv = (double)xb[(size_t)c << 12];   // wave-uniform
            #pragma unroll
            for (int j = 0; j < 8; ++j) {
                double t = xv - (double)er[c*KCODES + j];
                dd[j] = fma(t, t, dd[j]);
            }
        }
        double bd = 1e300; int bk = 0;
        #pragma unroll
        for (int j = 0; j < 8; ++j) {
            const int kk = lane*8 + j;
            if (dd[j] < bd) { bd = dd[j]; bk = kk; }
        }
        for (int off = 32; off; off >>= 1) {
            double od = __shfl_xor(bd, off);
            int    ok = __shfl_xor(bk, off);
            if (od < bd || (od == bd && ok < bk)) { bd = od; bk = ok; }
        }
        if (lane == 0) { ind_buf[n] = bk; out[OFF_IND + n] = (float)bk; }
    }
}

// ---------------------------------------------------------------- stats via MFMA: sum[c][k] = X^T . OneHot(ind)
// hi-only f16 (proven r9/r10)
__global__ __launch_bounds__(512) void k_stats(const float* __restrict__ in,
    const int* __restrict__ ind_buf, float* __restrict__ p_sum, float* __restrict__ p_cnt)
{
    __shared__ __align__(16) char xsm[2][CDIM*128];   // row c: [hi 32p | unused], byte ^= (c&7)<<4
    __shared__ int   ind_lds[2][32];
    __shared__ float s_cnt[KCODES];

    const int tid = threadIdx.x;
    const int wg  = blockIdx.x;
    const int n0  = wg << 10;                 // 1024 points, all same batch b
    const int b   = n0 >> 12;
    const float* inb = in + ((size_t)b << 18) + (n0 & 4095);

    for (int i = tid; i < KCODES; i += 512) s_cnt[i] = 0.f;

    const int sc  = tid >> 3;                 // staging: channel 0..63
    const int sp  = (tid & 7) << 2;           // 4-point slot
    const int sxr = (sc & 7) << 4;
    const int wb_hi = sc*128 + ((sp*2) ^ sxr);

    const int w  = tid >> 6, l = tid & 63;
    const int g  = l >> 4,  lc = l & 15;
    const int k0w = w << 6;                   // wave's 64-code band

    f32x4 acc[4][4];
    #pragma unroll
    for (int ci = 0; ci < 4; ++ci)
        #pragma unroll
        for (int kt = 0; kt < 4; ++kt) acc[ci][kt] = (f32x4){0.f, 0.f, 0.f, 0.f};

    // prologue: stage chunk 0
    {
        const float4 xv = *(const float4*)(inb + (size_t)sc*4096 + sp);
        half4v h;
        #pragma unroll
        for (int i = 0; i < 4; ++i) h[i] = (_Float16)(((const float*)&xv)[i]);
        *(half4v*)(&xsm[0][0] + wb_hi) = h;
        if (tid < 8) *(int4*)&ind_lds[0][tid*4] = *(const int4*)(ind_buf + n0 + tid*4);
    }

    for (int t = 0; t < 32; ++t) {
        __syncthreads();
        float4 nxt; int4 niv;
        if (t < 31) {
            nxt = *(const float4*)(inb + (size_t)sc*4096 + (t+1)*32 + sp);
            if (tid < 8) niv = *(const int4*)(ind_buf + n0 + (t+1)*32 + tid*4);
        }
        if (tid < 32) atomicAdd(&s_cnt[ind_lds[t & 1][tid]], 1.f);

        const char* xb = &xsm[t & 1][0];
        half8v ah[4];
        #pragma unroll
        for (int ci = 0; ci < 4; ++ci) {
            const int c  = (ci << 4) + lc;
            const int xr = (c & 7) << 4;
            ah[ci] = *(const half8v*)(xb + c*128 + ((g*16) ^ xr));
        }
        int idv[8];
        *(int4*)&idv[0] = *(const int4*)&ind_lds[t & 1][g*8];
        *(int4*)&idv[4] = *(const int4*)&ind_lds[t & 1][g*8 + 4];
        #pragma unroll
        for (int kt = 0; kt < 4; ++kt) {
            const int tgt = k0w + (kt << 4) + lc;
            half8v bf;
            #pragma unroll
            for (int j = 0; j < 8; ++j) bf[j] = (idv[j] == tgt) ? (_Float16)1.0f : (_Float16)0.0f;
            #pragma unroll
            for (int ci = 0; ci < 4; ++ci)
                acc[ci][kt] = __builtin_amdgcn_mfma_f32_16x16x32_f16(ah[ci], bf, acc[ci][kt], 0, 0, 0);
        }
        if (t < 31) {
            half4v h;
            #pragma unroll
            for (int i = 0; i < 4; ++i) h[i] = (_Float16)(((const float*)&nxt)[i]);
            *(half4v*)(&xsm[(t+1) & 1][0] + wb_hi) = h;
            if (tid < 8) *(int4*)&ind_lds[(t+1) & 1][tid*4] = niv;
        }
    }
    __syncthreads();

    float* ps = p_sum + (size_t)wg * (CDIM*KCODES);
    #pragma unroll
    for (int ci = 0; ci < 4; ++ci)
        #pragma unroll
        for (int kt = 0; kt < 4; ++kt)
            #pragma unroll
            for (int rr = 0; rr < 4; ++rr)
                ps[((ci << 4) + (g << 2) + rr)*KCODES + k0w + (kt << 4) + lc] = acc[ci][kt][rr];
    float* pc = p_cnt + wg * KCODES;
    for (int i = tid; i < KCODES; i += 512) pc[i] = s_cnt[i];
}

// ---------------------------------------------------------------- reduce stage 1: 256 -> 8 partials
__global__ __launch_bounds__(256) void k_reduce1(const float* __restrict__ p_sum,
    const float* __restrict__ p_cnt, float* __restrict__ partial8,
    float* __restrict__ cnt8, int wsl)
{
    const int ic = blockIdx.x & 31, ws = blockIdx.x >> 5;
    const int i4 = ic*1024 + threadIdx.x*4;
    const float* base = p_sum + (size_t)ws*wsl*(CDIM*KCODES) + i4;
    float4 s = make_float4(0.f, 0.f, 0.f, 0.f);
    for (int w = 0; w < wsl; ++w) {
        const float4 v = *(const float4*)(base + (size_t)w*(CDIM*KCODES));
        s.x += v.x; s.y += v.y; s.z += v.z; s.w += v.w;
    }
    *(float4*)(partial8 + ws*(CDIM*KCODES) + i4) = s;
    if (ic == 0) {
        for (int k = threadIdx.x; k < KCODES; k += 256) {
            float c = 0.f;
            for (int w = 0; w < wsl; ++w) c += p_cnt[(ws*wsl + w)*KCODES + k];
            cnt8[ws*KCODES + k] = c;
        }
    }
}

// ---------------------------------------------------------------- final: fused reduce2 + scalars + emb outputs
__global__ __launch_bounds__(512) void k_final(const float* __restrict__ partial8,
    const float* __restrict__ cnt8, const float* __restrict__ csz,
    const float* __restrict__ eavg, const float* __restrict__ diff_acc,
    float* __restrict__ out)
{
    __shared__ float red[512];
    __shared__ float cs_lds[512];
    const int k = threadIdx.x;
    float c = 0.f;
    #pragma unroll
    for (int p = 0; p < 8; ++p) c += cnt8[p*KCODES + k];
    const float ncs = csz[k]*0.99f + 0.01f*c;
    if (blockIdx.x == 0) out[OFF_CSZ + k] = ncs;
    red[k] = ncs;
    __syncthreads();
    for (int s = 256; s > 0; s >>= 1) { if (k < s) red[k] += red[k+s]; __syncthreads(); }
    const float n = red[0];
    cs_lds[k] = (ncs + 1e-5f) / (n + 0.00512f) * n;
    if (blockIdx.x == 0 && k == 0) out[OFF_DIFF] = diff_acc[0] * (1.f/16777216.f);
    __syncthreads();
    if (k < 256) {
        const int i = (blockIdx.x*256 + k)*4;        // 32*256*4 = 32768
        float4 s4 = make_float4(0.f, 0.f, 0.f, 0.f);
        #pragma unroll
        for (int p = 0; p < 8; ++p) {
            const float4 v = *(const float4*)(partial8 + p*(CDIM*KCODES) + i);
            s4.x += v.x; s4.y += v.y; s4.z += v.z; s4.w += v.w;
        }
        const float4 ea = *(const float4*)(eavg + i);
        const float a0 = ea.x*0.99f + 0.01f*s4.x;
        const float a1 = ea.y*0.99f + 0.01f*s4.y;
        const float a2 = ea.z*0.99f + 0.01f*s4.z;
        const float a3 = ea.w*0.99f + 0.01f*s4.w;
        const int kb = i & (KCODES-1);
        out[OFF_AVG + i]     = a0;  out[OFF_AVG + i + 1] = a1;
        out[OFF_AVG + i + 2] = a2;  out[OFF_AVG + i + 3] = a3;
        out[OFF_EMB + i]     = a0 / cs_lds[kb];
        out[OFF_EMB + i + 1] = a1 / cs_lds[kb + 1];
        out[OFF_EMB + i + 2] = a2 / cs_lds[kb + 2];
        out[OFF_EMB + i + 3] = a3 / cs_lds[kb + 3];
    }
}

// ---------------------------------------------------------------- quantize output (NCHW, coalesced)
__global__ void k_quant(const float* __restrict__ emb, const int* __restrict__ ind_buf,
                        float* __restrict__ out)
{
    const int gid = blockIdx.x*blockDim.x + threadIdx.x;
    const int i  = gid << 2;
    const int hw = i & 4095;
    const int c  = (i >> 12) & 63;
    const int b  = i >> 18;
    const int n  = (b << 12) + hw;
    const int4 iv = *(const int4*)(ind_buf + n);
    const float* er = emb + (c << 9);
    float4 o = make_float4(er[iv.x], er[iv.y], er[iv.z], er[iv.w]);
    *(float4*)(out + i) = o;
}

// ----------------------------------------------------------------
extern "C" void kernel_launch(void* const* d_in, const int* in_sizes, int n_in,
                              void* d_out, int out_size, void* d_ws, size_t ws_size,
                              hipStream_t stream)
{
    const float* in   = (const float*)d_in[0];
    const float* emb  = (const float*)d_in[1];
    const float* csz  = (const float*)d_in[2];
    const float* eavg = (const float*)d_in[3];
    float* out = (float*)d_out;
    char* ws = (char*)d_ws;

    // workspace layout (16B-aligned)
    int*      ind      = (int*)(ws + 2048);               //   1 MiB
    float*    diff_acc = (float*)(ws + 1050624);          //   4 B
    unsigned* nflag    = (unsigned*)(ws + 1050640);       //   4 B
    int*      flaglist = (int*)(ws + 1050656);            //   256 KiB
    const size_t off_part = 1447968;
    const int swgs = 256;
    float* p_sum    = (float*)(ws + off_part);
    float* p_cnt    = (float*)(ws + off_part + (size_t)swgs*(CDIM*KCODES)*4);
    float* partial8 = (float*)(ws + off_part + (size_t)swgs*133120);
    float* cnt8     = (float*)(ws + off_part + (size_t)swgs*133120 + 1048576);

    hipMemsetAsync(ws + 1050624, 0, 32, stream);          // diff_acc + nflag

    hipLaunchKernelGGL(k_main,    dim3(256),   dim3(1024), 0, stream, in, emb, out, ind, diff_acc, nflag, flaglist);
    hipLaunchKernelGGL(k_refine,  dim3(256),   dim3(256),  0, stream, in, emb, nflag, flaglist, ind, out);
    hipLaunchKernelGGL(k_quant,   dim3(16384), dim3(256),  0, stream, emb, ind, out);
    hipLaunchKernelGGL(k_stats,   dim3(256),   dim3(512),  0, stream, in, ind, p_sum, p_cnt);
    hipLaunchKernelGGL(k_reduce1, dim3(256),   dim3(256),  0, stream, p_sum, p_cnt, partial8, cnt8, swgs >> 3);
    hipLaunchKernelGGL(k_final,   dim3(32),    dim3(512),  0, stream, partial8, cnt8, csz, eavg, diff_acc, out);
}

// Round 16
// 233.932 us; speedup vs baseline: 1.2991x; 1.2991x over previous
//
#include <hip/hip_runtime.h>
#include <cstdint>
#include <cstddef>

typedef _Float16 half4v __attribute__((ext_vector_type(4)));
typedef _Float16 half8v __attribute__((ext_vector_type(8)));
typedef float    f32x4  __attribute__((ext_vector_type(4)));

#define N_PTS   262144
#define CDIM    64
#define KCODES  512
#define TAUA    5e-3f          // acc-units; true-dist gap = 2*acc gap -> 1e-2 (r10 proven)
#define FLAG_CAP 65536u

// output offsets (floats): out, diff, embedding_ind, new_embedding, new_cluster_size, new_embedding_avg
#define OFF_DIFF 16777216u
#define OFF_IND  16777217u
#define OFF_EMB  17039361u
#define OFF_CSZ  17072129u
#define OFF_AVG  17072641u

// ---------------------------------------------------------------- main: MFMA f16x2-split distances + argmin
// acc = ee/2 + (-x)*e  ->  dist = 2*acc + xx  (argmin equivalent in acc units)
// EXACT r10-proven kernel (102us, session best). Occupancy avenue closed after 6 experiments:
// LDS-shrink pays restaging (r7/r11/r12); 1024-thr WG gets hard 64-VGPR cap -> spills (r13/r15);
// ILP split neutral (r8). 512 thr / 256 WGs / VGPR 128 / 2 waves/SIMD is the structural floor here.
__global__ __launch_bounds__(512) void k_main(
    const float* __restrict__ in, const float* __restrict__ emb,
    float* __restrict__ out,
    int* __restrict__ ind_buf, float* __restrict__ diff_acc,
    unsigned* __restrict__ nflag, int* __restrict__ flaglist)
{
    // LDS: B_hi [64KiB] | B_lo [64KiB] | ee2 [2KiB]   (swizzled: byte ^= (col&7)<<4)
    __shared__ __align__(16) char bsm[133120];
    float* ee2_lds = (float*)(bsm + 131072);
    const int tid = threadIdx.x;

    // ---- stage codebook: fp32 -> f16 hi/lo, swizzled; ee2 computed inline ----
    {
        const int col = tid;                 // 512 threads = 512 cols
        const int xr  = (col & 7) << 4;
        float s = 0.f;
        #pragma unroll
        for (int c0 = 0; c0 < CDIM; c0 += 4) {
            float v[4];
            #pragma unroll
            for (int i = 0; i < 4; ++i) v[i] = emb[(c0 + i)*KCODES + col];
            half4v h, lo;
            #pragma unroll
            for (int i = 0; i < 4; ++i) {
                s = fmaf(v[i], v[i], s);
                _Float16 hh = (_Float16)v[i];
                h[i]  = hh;
                lo[i] = (_Float16)(v[i] - (float)hh);
            }
            const int wb = col*128 + ((c0*2) ^ xr);
            *(half4v*)(bsm + wb)         = h;
            *(half4v*)(bsm + 65536 + wb) = lo;
        }
        ee2_lds[col] = 0.5f * s;
    }
    __syncthreads();

    const int w  = tid >> 6, l = tid & 63;
    const int g  = l >> 4,  lc = l & 15;

    for (int r = 0; r < 2; ++r) {
        const int pbase = (blockIdx.x << 10) + (r << 9) + (w << 6);  // 64 points/wave
        const int b     = pbase >> 12;
        const float* inb = in + ((size_t)b << 18) + ((pbase & 4095) + lc);

        // ---- A fragments: negated x, exact f16 split; xx accumulated on the fly ----
        half8v ah[4][2], al[4][2];
        float xs = 0.f;
        #pragma unroll
        for (int t = 0; t < 4; ++t)
            #pragma unroll
            for (int s = 0; s < 2; ++s)
                #pragma unroll
                for (int j = 0; j < 8; ++j) {
                    const int c = s*32 + g*8 + j;
                    const float x = inb[(size_t)c*4096 + t*16];
                    xs = fmaf(x, x, xs);
                    const float xf = -x;
                    const _Float16 hh = (_Float16)xf;
                    ah[t][s][j] = hh;
                    al[t][s][j] = (_Float16)(xf - (float)hh);
                }

        float d1[4][4], d2[4][4]; int k1[4][4];
        #pragma unroll
        for (int t = 0; t < 4; ++t)
            #pragma unroll
            for (int rr = 0; rr < 4; ++rr) { d1[t][rr] = 3.4e38f; d2[t][rr] = 3.4e38f; k1[t][rr] = 0; }

        for (int ct = 0; ct < 32; ++ct) {
            const int col  = (ct << 4) + lc;
            const float sd = ee2_lds[col];
            const int rb   = col*128 + ((g*16) ^ ((col & 7) << 4));
            half8v bh0 = *(const half8v*)(bsm + rb);
            half8v bh1 = *(const half8v*)(bsm + (rb ^ 64));
            half8v bl0 = *(const half8v*)(bsm + 65536 + rb);
            half8v bl1 = *(const half8v*)(bsm + 65536 + (rb ^ 64));

            #pragma unroll
            for (int t = 0; t < 4; ++t) {
                // two independent 3-deep chains (K-halves s=0 / s=1)
                f32x4 acc0 = {sd, sd, sd, sd};
                f32x4 acc1 = {0.f, 0.f, 0.f, 0.f};
                acc0 = __builtin_amdgcn_mfma_f32_16x16x32_f16(al[t][0], bh0, acc0, 0, 0, 0);
                acc1 = __builtin_amdgcn_mfma_f32_16x16x32_f16(al[t][1], bh1, acc1, 0, 0, 0);
                acc0 = __builtin_amdgcn_mfma_f32_16x16x32_f16(ah[t][0], bl0, acc0, 0, 0, 0);
                acc1 = __builtin_amdgcn_mfma_f32_16x16x32_f16(ah[t][1], bl1, acc1, 0, 0, 0);
                acc0 = __builtin_amdgcn_mfma_f32_16x16x32_f16(ah[t][0], bh0, acc0, 0, 0, 0);
                acc1 = __builtin_amdgcn_mfma_f32_16x16x32_f16(ah[t][1], bh1, acc1, 0, 0, 0);
                #pragma unroll
                for (int rr = 0; rr < 4; ++rr) {
                    const float d = acc0[rr] + acc1[rr];
                    const bool cc = d < d1[t][rr];
                    d2[t][rr] = fminf(d2[t][rr], fmaxf(d, d1[t][rr]));
                    d1[t][rr] = fminf(d1[t][rr], d);
                    k1[t][rr] = cc ? col : k1[t][rr];
                }
            }
        }

        // ---- cross-lane best-2 merge over the 16 col-lanes ----
        #pragma unroll
        for (int m = 1; m <= 8; m <<= 1) {
            #pragma unroll
            for (int t = 0; t < 4; ++t)
                #pragma unroll
                for (int rr = 0; rr < 4; ++rr) {
                    const float od1 = __shfl_xor(d1[t][rr], m);
                    const int   ok1 = __shfl_xor(k1[t][rr], m);
                    const float od2 = __shfl_xor(d2[t][rr], m);
                    const float nd2 = fminf(fmaxf(d1[t][rr], od1), fminf(d2[t][rr], od2));
                    const bool take = (od1 < d1[t][rr]) || (od1 == d1[t][rr] && ok1 < k1[t][rr]);
                    d1[t][rr] = take ? od1 : d1[t][rr];
                    k1[t][rr] = take ? ok1 : k1[t][rr];
                    d2[t][rr] = nd2;
                }
        }

        // ---- outputs: indices, near-tie flags, diff partial ----
        float ds = 0.f;
        if (lc == 0) {
            #pragma unroll
            for (int t = 0; t < 4; ++t) {
                const int nb = pbase + t*16 + (g << 2);
                int4 iv = make_int4(k1[t][0], k1[t][1], k1[t][2], k1[t][3]);
                *(int4*)(ind_buf + nb) = iv;
                #pragma unroll
                for (int rr = 0; rr < 4; ++rr) {
                    out[OFF_IND + nb + rr] = (float)k1[t][rr];
                    ds += d1[t][rr];
                    if (d2[t][rr] - d1[t][rr] < TAUA) {
                        unsigned ix = atomicAdd(nflag, 1u);
                        if (ix < FLAG_CAP) flaglist[ix] = nb + rr;
                    }
                }
            }
        }
        #pragma unroll
        for (int m = 1; m < 64; m <<= 1) {
            ds += __shfl_xor(ds, m);
            xs += __shfl_xor(xs, m);
        }
        if (l == 0) atomicAdd(diff_acc, 2.f*ds + xs);
    }
}

// ---------------------------------------------------------------- f64 exact re-scan for near-ties
__global__ void k_refine(const float* __restrict__ in, const float* __restrict__ emb,
                         const unsigned* __restrict__ nflag, const int* __restrict__ flaglist,
                         int* __restrict__ ind_buf, float* __restrict__ out)
{
    const int gtid = blockIdx.x*blockDim.x + threadIdx.x;
    const int wid  = gtid >> 6;
    const int lane = threadIdx.x & 63;
    const int nw   = (gridDim.x * blockDim.x) >> 6;
    unsigned nf = *nflag; if (nf > FLAG_CAP) nf = FLAG_CAP;
    for (unsigned f = wid; f < nf; f += nw) {
        const int n = flaglist[f];
        const int b = n >> 12, hw = n & 4095;
        const float* xb = in + ((size_t)b << 18) + hw;
        const float* er = emb + lane*8;
        double dd[8] = {0,0,0,0,0,0,0,0};
        for (int c = 0; c < CDIM; ++c) {
            const double xv = (double)xb[(size_t)c << 12];   // wave-uniform
            #pragma unroll
            for (int j = 0; j < 8; ++j) {
                double t = xv - (double)er[c*KCODES + j];
                dd[j] = fma(t, t, dd[j]);
            }
        }
        double bd = 1e300; int bk = 0;
        #pragma unroll
        for (int j = 0; j < 8; ++j) {
            const int kk = lane*8 + j;
            if (dd[j] < bd) { bd = dd[j]; bk = kk; }
        }
        for (int off = 32; off; off >>= 1) {
            double od = __shfl_xor(bd, off);
            int    ok = __shfl_xor(bk, off);
            if (od < bd || (od == bd && ok < bk)) { bd = od; bk = ok; }
        }
        if (lane == 0) { ind_buf[n] = bk; out[OFF_IND + n] = (float)bk; }
    }
}

// ---------------------------------------------------------------- stats via MFMA: sum[c][k] = X^T . OneHot(ind)
// hi-only f16 (proven r9/r10). chunk = points per WG (parameterized for occupancy probe:
// 512 pts/WG x 512 WGs -> 2 WGs/CU, barrier phases interleave across resident WGs).
__global__ __launch_bounds__(512) void k_stats(const float* __restrict__ in,
    const int* __restrict__ ind_buf, float* __restrict__ p_sum, float* __restrict__ p_cnt, int chunk)
{
    __shared__ __align__(16) char xsm[2][CDIM*128];   // row c: [hi 32p | unused], byte ^= (c&7)<<4
    __shared__ int   ind_lds[2][32];
    __shared__ float s_cnt[KCODES];

    const int tid = threadIdx.x;
    const int wg  = blockIdx.x;
    const int n0  = wg * chunk;               // chunk | 4096 -> same batch b
    const int b   = n0 >> 12;
    const float* inb = in + ((size_t)b << 18) + (n0 & 4095);
    const int nt  = chunk >> 5;

    for (int i = tid; i < KCODES; i += 512) s_cnt[i] = 0.f;

    const int sc  = tid >> 3;                 // staging: channel 0..63
    const int sp  = (tid & 7) << 2;           // 4-point slot
    const int sxr = (sc & 7) << 4;
    const int wb_hi = sc*128 + ((sp*2) ^ sxr);

    const int w  = tid >> 6, l = tid & 63;
    const int g  = l >> 4,  lc = l & 15;
    const int k0w = w << 6;                   // wave's 64-code band

    f32x4 acc[4][4];
    #pragma unroll
    for (int ci = 0; ci < 4; ++ci)
        #pragma unroll
        for (int kt = 0; kt < 4; ++kt) acc[ci][kt] = (f32x4){0.f, 0.f, 0.f, 0.f};

    // prologue: stage chunk 0
    {
        const float4 xv = *(const float4*)(inb + (size_t)sc*4096 + sp);
        half4v h;
        #pragma unroll
        for (int i = 0; i < 4; ++i) h[i] = (_Float16)(((const float*)&xv)[i]);
        *(half4v*)(&xsm[0][0] + wb_hi) = h;
        if (tid < 8) *(int4*)&ind_lds[0][tid*4] = *(const int4*)(ind_buf + n0 + tid*4);
    }

    for (int t = 0; t < nt; ++t) {
        __syncthreads();
        float4 nxt; int4 niv;
        if (t < nt-1) {
            nxt = *(const float4*)(inb + (size_t)sc*4096 + (t+1)*32 + sp);
            if (tid < 8) niv = *(const int4*)(ind_buf + n0 + (t+1)*32 + tid*4);
        }
        if (tid < 32) atomicAdd(&s_cnt[ind_lds[t & 1][tid]], 1.f);

        const char* xb = &xsm[t & 1][0];
        half8v ah[4];
        #pragma unroll
        for (int ci = 0; ci < 4; ++ci) {
            const int c  = (ci << 4) + lc;
            const int xr = (c & 7) << 4;
            ah[ci] = *(const half8v*)(xb + c*128 + ((g*16) ^ xr));
        }
        int idv[8];
        *(int4*)&idv[0] = *(const int4*)&ind_lds[t & 1][g*8];
        *(int4*)&idv[4] = *(const int4*)&ind_lds[t & 1][g*8 + 4];
        #pragma unroll
        for (int kt = 0; kt < 4; ++kt) {
            const int tgt = k0w + (kt << 4) + lc;
            half8v bf;
            #pragma unroll
            for (int j = 0; j < 8; ++j) bf[j] = (idv[j] == tgt) ? (_Float16)1.0f : (_Float16)0.0f;
            #pragma unroll
            for (int ci = 0; ci < 4; ++ci)
                acc[ci][kt] = __builtin_amdgcn_mfma_f32_16x16x32_f16(ah[ci], bf, acc[ci][kt], 0, 0, 0);
        }
        if (t < nt-1) {
            half4v h;
            #pragma unroll
            for (int i = 0; i < 4; ++i) h[i] = (_Float16)(((const float*)&nxt)[i]);
            *(half4v*)(&xsm[(t+1) & 1][0] + wb_hi) = h;
            if (tid < 8) *(int4*)&ind_lds[(t+1) & 1][tid*4] = niv;
        }
    }
    __syncthreads();

    float* ps = p_sum + (size_t)wg * (CDIM*KCODES);
    #pragma unroll
    for (int ci = 0; ci < 4; ++ci)
        #pragma unroll
        for (int kt = 0; kt < 4; ++kt)
            #pragma unroll
            for (int rr = 0; rr < 4; ++rr)
                ps[((ci << 4) + (g << 2) + rr)*KCODES + k0w + (kt << 4) + lc] = acc[ci][kt][rr];
    float* pc = p_cnt + wg * KCODES;
    for (int i = tid; i < KCODES; i += 512) pc[i] = s_cnt[i];
}

// ---------------------------------------------------------------- reduce stage 1: swgs -> 8 partials
__global__ __launch_bounds__(256) void k_reduce1(const float* __restrict__ p_sum,
    const float* __restrict__ p_cnt, float* __restrict__ partial8,
    float* __restrict__ cnt8, int wsl)
{
    const int ic = blockIdx.x & 31, ws = blockIdx.x >> 5;
    const int i4 = ic*1024 + threadIdx.x*4;
    const float* base = p_sum + (size_t)ws*wsl*(CDIM*KCODES) + i4;
    float4 s = make_float4(0.f, 0.f, 0.f, 0.f);
    for (int w = 0; w < wsl; ++w) {
        const float4 v = *(const float4*)(base + (size_t)w*(CDIM*KCODES));
        s.x += v.x; s.y += v.y; s.z += v.z; s.w += v.w;
    }
    *(float4*)(partial8 + ws*(CDIM*KCODES) + i4) = s;
    if (ic == 0) {
        for (int k = threadIdx.x; k < KCODES; k += 256) {
            float c = 0.f;
            for (int w = 0; w < wsl; ++w) c += p_cnt[(ws*wsl + w)*KCODES + k];
            cnt8[ws*KCODES + k] = c;
        }
    }
}

// ---------------------------------------------------------------- final: fused reduce2 + scalars + emb outputs
__global__ __launch_bounds__(512) void k_final(const float* __restrict__ partial8,
    const float* __restrict__ cnt8, const float* __restrict__ csz,
    const float* __restrict__ eavg, const float* __restrict__ diff_acc,
    float* __restrict__ out)
{
    __shared__ float red[512];
    __shared__ float cs_lds[512];
    const int k = threadIdx.x;
    float c = 0.f;
    #pragma unroll
    for (int p = 0; p < 8; ++p) c += cnt8[p*KCODES + k];
    const float ncs = csz[k]*0.99f + 0.01f*c;
    if (blockIdx.x == 0) out[OFF_CSZ + k] = ncs;
    red[k] = ncs;
    __syncthreads();
    for (int s = 256; s > 0; s >>= 1) { if (k < s) red[k] += red[k+s]; __syncthreads(); }
    const float n = red[0];
    cs_lds[k] = (ncs + 1e-5f) / (n + 0.00512f) * n;
    if (blockIdx.x == 0 && k == 0) out[OFF_DIFF] = diff_acc[0] * (1.f/16777216.f);
    __syncthreads();
    if (k < 256) {
        const int i = (blockIdx.x*256 + k)*4;        // 32*256*4 = 32768
        float4 s4 = make_float4(0.f, 0.f, 0.f, 0.f);
        #pragma unroll
        for (int p = 0; p < 8; ++p) {
            const float4 v = *(const float4*)(partial8 + p*(CDIM*KCODES) + i);
            s4.x += v.x; s4.y += v.y; s4.z += v.z; s4.w += v.w;
        }
        const float4 ea = *(const float4*)(eavg + i);
        const float a0 = ea.x*0.99f + 0.01f*s4.x;
        const float a1 = ea.y*0.99f + 0.01f*s4.y;
        const float a2 = ea.z*0.99f + 0.01f*s4.z;
        const float a3 = ea.w*0.99f + 0.01f*s4.w;
        const int kb = i & (KCODES-1);
        out[OFF_AVG + i]     = a0;  out[OFF_AVG + i + 1] = a1;
        out[OFF_AVG + i + 2] = a2;  out[OFF_AVG + i + 3] = a3;
        out[OFF_EMB + i]     = a0 / cs_lds[kb];
        out[OFF_EMB + i + 1] = a1 / cs_lds[kb + 1];
        out[OFF_EMB + i + 2] = a2 / cs_lds[kb + 2];
        out[OFF_EMB + i + 3] = a3 / cs_lds[kb + 3];
    }
}

// ---------------------------------------------------------------- quantize output (NCHW, coalesced)
__global__ void k_quant(const float* __restrict__ emb, const int* __restrict__ ind_buf,
                        float* __restrict__ out)
{
    const int gid = blockIdx.x*blockDim.x + threadIdx.x;
    const int i  = gid << 2;
    const int hw = i & 4095;
    const int c  = (i >> 12) & 63;
    const int b  = i >> 18;
    const int n  = (b << 12) + hw;
    const int4 iv = *(const int4*)(ind_buf + n);
    const float* er = emb + (c << 9);
    float4 o = make_float4(er[iv.x], er[iv.y], er[iv.z], er[iv.w]);
    *(float4*)(out + i) = o;
}

// ----------------------------------------------------------------
extern "C" void kernel_launch(void* const* d_in, const int* in_sizes, int n_in,
                              void* d_out, int out_size, void* d_ws, size_t ws_size,
                              hipStream_t stream)
{
    const float* in   = (const float*)d_in[0];
    const float* emb  = (const float*)d_in[1];
    const float* csz  = (const float*)d_in[2];
    const float* eavg = (const float*)d_in[3];
    float* out = (float*)d_out;
    char* ws = (char*)d_ws;

    // workspace layout (16B-aligned)
    int*      ind      = (int*)(ws + 2048);               //   1 MiB
    float*    diff_acc = (float*)(ws + 1050624);          //   4 B
    unsigned* nflag    = (unsigned*)(ws + 1050640);       //   4 B
    int*      flaglist = (int*)(ws + 1050656);            //   256 KiB
    const size_t off_part = 1447968;
    // adaptive partial count: try 512 (2 WGs/CU for k_stats), fall back if ws too small
    int swgs = 512;
    while (swgs > 8 && off_part + (size_t)swgs*133120 + 1048576 + 16384 > ws_size) swgs >>= 1;
    float* p_sum    = (float*)(ws + off_part);
    float* p_cnt    = (float*)(ws + off_part + (size_t)swgs*(CDIM*KCODES)*4);
    float* partial8 = (float*)(ws + off_part + (size_t)swgs*133120);
    float* cnt8     = (float*)(ws + off_part + (size_t)swgs*133120 + 1048576);

    hipMemsetAsync(ws + 1050624, 0, 32, stream);          // diff_acc + nflag

    hipLaunchKernelGGL(k_main,    dim3(256),   dim3(512), 0, stream, in, emb, out, ind, diff_acc, nflag, flaglist);
    hipLaunchKernelGGL(k_refine,  dim3(256),   dim3(256), 0, stream, in, emb, nflag, flaglist, ind, out);
    hipLaunchKernelGGL(k_quant,   dim3(16384), dim3(256), 0, stream, emb, ind, out);
    hipLaunchKernelGGL(k_stats,   dim3(swgs),  dim3(512), 0, stream, in, ind, p_sum, p_cnt, N_PTS/swgs);
    hipLaunchKernelGGL(k_reduce1, dim3(256),   dim3(256), 0, stream, p_sum, p_cnt, partial8, cnt8, swgs >> 3);
    hipLaunchKernelGGL(k_final,   dim3(32),    dim3(512), 0, stream, partial8, cnt8, csz, eavg, diff_acc, out);
}

// Round 17
// 197.131 us; speedup vs baseline: 1.5417x; 1.1867x over previous
//
#include <hip/hip_runtime.h>
#include <cstdint>
#include <cstddef>

typedef _Float16 half4v __attribute__((ext_vector_type(4)));
typedef _Float16 half8v __attribute__((ext_vector_type(8)));
typedef float    f32x4  __attribute__((ext_vector_type(4)));

#define N_PTS   262144
#define CDIM    64
#define KCODES  512
#define TAUA    5e-3f          // acc-units; true-dist gap = 2*acc gap -> 1e-2 (r10 proven)
#define FLAG_CAP 65536u
#define STATS_WGS 256

// output offsets (floats): out, diff, embedding_ind, new_embedding, new_cluster_size, new_embedding_avg
#define OFF_DIFF 16777216u
#define OFF_IND  16777217u
#define OFF_EMB  17039361u
#define OFF_CSZ  17072129u
#define OFF_AVG  17072641u

// ---------------------------------------------------------------- main: MFMA f16x2-split distances + argmin
// acc = ee/2 + (-x)*e  ->  dist = 2*acc + xx  (argmin equivalent in acc units)
// EXACT r10-proven kernel (102us). k_main structural floor established over 6 experiments
// (r7/r11/r12 LDS-shrink pays restaging; r13/r15 1024-thr WG hits 64-VGPR cap; r8 ILP neutral).
__global__ __launch_bounds__(512) void k_main(
    const float* __restrict__ in, const float* __restrict__ emb,
    float* __restrict__ out,
    int* __restrict__ ind_buf, float* __restrict__ diff_acc,
    unsigned* __restrict__ nflag, int* __restrict__ flaglist)
{
    // LDS: B_hi [64KiB] | B_lo [64KiB] | ee2 [2KiB]   (swizzled: byte ^= (col&7)<<4)
    __shared__ __align__(16) char bsm[133120];
    float* ee2_lds = (float*)(bsm + 131072);
    const int tid = threadIdx.x;

    // ---- stage codebook: fp32 -> f16 hi/lo, swizzled; ee2 computed inline ----
    {
        const int col = tid;                 // 512 threads = 512 cols
        const int xr  = (col & 7) << 4;
        float s = 0.f;
        #pragma unroll
        for (int c0 = 0; c0 < CDIM; c0 += 4) {
            float v[4];
            #pragma unroll
            for (int i = 0; i < 4; ++i) v[i] = emb[(c0 + i)*KCODES + col];
            half4v h, lo;
            #pragma unroll
            for (int i = 0; i < 4; ++i) {
                s = fmaf(v[i], v[i], s);
                _Float16 hh = (_Float16)v[i];
                h[i]  = hh;
                lo[i] = (_Float16)(v[i] - (float)hh);
            }
            const int wb = col*128 + ((c0*2) ^ xr);
            *(half4v*)(bsm + wb)         = h;
            *(half4v*)(bsm + 65536 + wb) = lo;
        }
        ee2_lds[col] = 0.5f * s;
    }
    __syncthreads();

    const int w  = tid >> 6, l = tid & 63;
    const int g  = l >> 4,  lc = l & 15;

    for (int r = 0; r < 2; ++r) {
        const int pbase = (blockIdx.x << 10) + (r << 9) + (w << 6);  // 64 points/wave
        const int b     = pbase >> 12;
        const float* inb = in + ((size_t)b << 18) + ((pbase & 4095) + lc);

        // ---- A fragments: negated x, exact f16 split; xx accumulated on the fly ----
        half8v ah[4][2], al[4][2];
        float xs = 0.f;
        #pragma unroll
        for (int t = 0; t < 4; ++t)
            #pragma unroll
            for (int s = 0; s < 2; ++s)
                #pragma unroll
                for (int j = 0; j < 8; ++j) {
                    const int c = s*32 + g*8 + j;
                    const float x = inb[(size_t)c*4096 + t*16];
                    xs = fmaf(x, x, xs);
                    const float xf = -x;
                    const _Float16 hh = (_Float16)xf;
                    ah[t][s][j] = hh;
                    al[t][s][j] = (_Float16)(xf - (float)hh);
                }

        float d1[4][4], d2[4][4]; int k1[4][4];
        #pragma unroll
        for (int t = 0; t < 4; ++t)
            #pragma unroll
            for (int rr = 0; rr < 4; ++rr) { d1[t][rr] = 3.4e38f; d2[t][rr] = 3.4e38f; k1[t][rr] = 0; }

        for (int ct = 0; ct < 32; ++ct) {
            const int col  = (ct << 4) + lc;
            const float sd = ee2_lds[col];
            const int rb   = col*128 + ((g*16) ^ ((col & 7) << 4));
            half8v bh0 = *(const half8v*)(bsm + rb);
            half8v bh1 = *(const half8v*)(bsm + (rb ^ 64));
            half8v bl0 = *(const half8v*)(bsm + 65536 + rb);
            half8v bl1 = *(const half8v*)(bsm + 65536 + (rb ^ 64));

            #pragma unroll
            for (int t = 0; t < 4; ++t) {
                // two independent 3-deep chains (K-halves s=0 / s=1)
                f32x4 acc0 = {sd, sd, sd, sd};
                f32x4 acc1 = {0.f, 0.f, 0.f, 0.f};
                acc0 = __builtin_amdgcn_mfma_f32_16x16x32_f16(al[t][0], bh0, acc0, 0, 0, 0);
                acc1 = __builtin_amdgcn_mfma_f32_16x16x32_f16(al[t][1], bh1, acc1, 0, 0, 0);
                acc0 = __builtin_amdgcn_mfma_f32_16x16x32_f16(ah[t][0], bl0, acc0, 0, 0, 0);
                acc1 = __builtin_amdgcn_mfma_f32_16x16x32_f16(ah[t][1], bl1, acc1, 0, 0, 0);
                acc0 = __builtin_amdgcn_mfma_f32_16x16x32_f16(ah[t][0], bh0, acc0, 0, 0, 0);
                acc1 = __builtin_amdgcn_mfma_f32_16x16x32_f16(ah[t][1], bh1, acc1, 0, 0, 0);
                #pragma unroll
                for (int rr = 0; rr < 4; ++rr) {
                    const float d = acc0[rr] + acc1[rr];
                    const bool cc = d < d1[t][rr];
                    d2[t][rr] = fminf(d2[t][rr], fmaxf(d, d1[t][rr]));
                    d1[t][rr] = fminf(d1[t][rr], d);
                    k1[t][rr] = cc ? col : k1[t][rr];
                }
            }
        }

        // ---- cross-lane best-2 merge over the 16 col-lanes ----
        #pragma unroll
        for (int m = 1; m <= 8; m <<= 1) {
            #pragma unroll
            for (int t = 0; t < 4; ++t)
                #pragma unroll
                for (int rr = 0; rr < 4; ++rr) {
                    const float od1 = __shfl_xor(d1[t][rr], m);
                    const int   ok1 = __shfl_xor(k1[t][rr], m);
                    const float od2 = __shfl_xor(d2[t][rr], m);
                    const float nd2 = fminf(fmaxf(d1[t][rr], od1), fminf(d2[t][rr], od2));
                    const bool take = (od1 < d1[t][rr]) || (od1 == d1[t][rr] && ok1 < k1[t][rr]);
                    d1[t][rr] = take ? od1 : d1[t][rr];
                    k1[t][rr] = take ? ok1 : k1[t][rr];
                    d2[t][rr] = nd2;
                }
        }

        // ---- outputs: indices, near-tie flags, diff partial ----
        float ds = 0.f;
        if (lc == 0) {
            #pragma unroll
            for (int t = 0; t < 4; ++t) {
                const int nb = pbase + t*16 + (g << 2);
                int4 iv = make_int4(k1[t][0], k1[t][1], k1[t][2], k1[t][3]);
                *(int4*)(ind_buf + nb) = iv;
                #pragma unroll
                for (int rr = 0; rr < 4; ++rr) {
                    out[OFF_IND + nb + rr] = (float)k1[t][rr];
                    ds += d1[t][rr];
                    if (d2[t][rr] - d1[t][rr] < TAUA) {
                        unsigned ix = atomicAdd(nflag, 1u);
                        if (ix < FLAG_CAP) flaglist[ix] = nb + rr;
                    }
                }
            }
        }
        #pragma unroll
        for (int m = 1; m < 64; m <<= 1) {
            ds += __shfl_xor(ds, m);
            xs += __shfl_xor(xs, m);
        }
        if (l == 0) atomicAdd(diff_acc, 2.f*ds + xs);
    }
}

// ---------------------------------------------------------------- f64 exact re-scan for near-ties
__global__ void k_refine(const float* __restrict__ in, const float* __restrict__ emb,
                         const unsigned* __restrict__ nflag, const int* __restrict__ flaglist,
                         int* __restrict__ ind_buf, float* __restrict__ out)
{
    const int gtid = blockIdx.x*blockDim.x + threadIdx.x;
    const int wid  = gtid >> 6;
    const int lane = threadIdx.x & 63;
    const int nw   = (gridDim.x * blockDim.x) >> 6;
    unsigned nf = *nflag; if (nf > FLAG_CAP) nf = FLAG_CAP;
    for (unsigned f = wid; f < nf; f += nw) {
        const int n = flaglist[f];
        const int b = n >> 12, hw = n & 4095;
        const float* xb = in + ((size_t)b << 18) + hw;
        const float* er = emb + lane*8;
        double dd[8] = {0,0,0,0,0,0,0,0};
        for (int c = 0; c < CDIM; ++c) {
            const double xv = (double)xb[(size_t)c << 12];   // wave-uniform
            #pragma unroll
            for (int j = 0; j < 8; ++j) {
                double t = xv - (double)er[c*KCODES + j];
                dd[j] = fma(t, t, dd[j]);
            }
        }
        double bd = 1e300; int bk = 0;
        #pragma unroll
        for (int j = 0; j < 8; ++j) {
            const int kk = lane*8 + j;
            if (dd[j] < bd) { bd = dd[j]; bk = kk; }
        }
        for (int off = 32; off; off >>= 1) {
            double od = __shfl_xor(bd, off);
            int    ok = __shfl_xor(bk, off);
            if (od < bd || (od == bd && ok < bk)) { bd = od; bk = ok; }
        }
        if (lane == 0) { ind_buf[n] = bk; out[OFF_IND + n] = (float)bk; }
    }
}

// ---------------------------------------------------------------- fused tail: stats (blocks 0..255) + quantize (blocks 256..8447)
// stats: MFMA segment-sum, hi-only f16 (proven r9/r10, chunk=1024). quant: streaming gather-write.
// Independent after refine; grid-partitioned into one launch so the latency-bound stats phases
// overlap with the BW-bound quant stream on the same CUs (single stream forbids multi-kernel overlap).
__global__ __launch_bounds__(512) void k_tail(const float* __restrict__ in,
    const float* __restrict__ emb, const int* __restrict__ ind_buf,
    float* __restrict__ p_sum, float* __restrict__ p_cnt, float* __restrict__ out)
{
    __shared__ __align__(16) char xsm[2][CDIM*128];   // row c: [hi 32p | unused], byte ^= (c&7)<<4
    __shared__ int   ind_lds[2][32];
    __shared__ float s_cnt[KCODES];

    const int tid = threadIdx.x;

    if (blockIdx.x >= STATS_WGS) {
        // ---- quantize: out[b][c][hw] = emb[c][ind[b][hw]], 1 float4/thread ----
        const int gid = (blockIdx.x - STATS_WGS)*512 + tid;
        const int i  = gid << 2;
        const int hw = i & 4095;
        const int c  = (i >> 12) & 63;
        const int b  = i >> 18;
        const int n  = (b << 12) + hw;
        const int4 iv = *(const int4*)(ind_buf + n);
        const float* er = emb + (c << 9);
        float4 o = make_float4(er[iv.x], er[iv.y], er[iv.z], er[iv.w]);
        *(float4*)(out + i) = o;
        return;
    }

    // ---- stats body (r10-proven) ----
    const int wg  = blockIdx.x;
    const int n0  = wg << 10;                 // 1024 points, all same batch b
    const int b   = n0 >> 12;
    const float* inb = in + ((size_t)b << 18) + (n0 & 4095);

    for (int i = tid; i < KCODES; i += 512) s_cnt[i] = 0.f;

    const int sc  = tid >> 3;                 // staging: channel 0..63
    const int sp  = (tid & 7) << 2;           // 4-point slot
    const int sxr = (sc & 7) << 4;
    const int wb_hi = sc*128 + ((sp*2) ^ sxr);

    const int w  = tid >> 6, l = tid & 63;
    const int g  = l >> 4,  lc = l & 15;
    const int k0w = w << 6;                   // wave's 64-code band

    f32x4 acc[4][4];
    #pragma unroll
    for (int ci = 0; ci < 4; ++ci)
        #pragma unroll
        for (int kt = 0; kt < 4; ++kt) acc[ci][kt] = (f32x4){0.f, 0.f, 0.f, 0.f};

    // prologue: stage chunk 0
    {
        const float4 xv = *(const float4*)(inb + (size_t)sc*4096 + sp);
        half4v h;
        #pragma unroll
        for (int i = 0; i < 4; ++i) h[i] = (_Float16)(((const float*)&xv)[i]);
        *(half4v*)(&xsm[0][0] + wb_hi) = h;
        if (tid < 8) *(int4*)&ind_lds[0][tid*4] = *(const int4*)(ind_buf + n0 + tid*4);
    }

    for (int t = 0; t < 32; ++t) {
        __syncthreads();
        float4 nxt; int4 niv;
        if (t < 31) {
            nxt = *(const float4*)(inb + (size_t)sc*4096 + (t+1)*32 + sp);
            if (tid < 8) niv = *(const int4*)(ind_buf + n0 + (t+1)*32 + tid*4);
        }
        if (tid < 32) atomicAdd(&s_cnt[ind_lds[t & 1][tid]], 1.f);

        const char* xb = &xsm[t & 1][0];
        half8v ah[4];
        #pragma unroll
        for (int ci = 0; ci < 4; ++ci) {
            const int c  = (ci << 4) + lc;
            const int xr = (c & 7) << 4;
            ah[ci] = *(const half8v*)(xb + c*128 + ((g*16) ^ xr));
        }
        int idv[8];
        *(int4*)&idv[0] = *(const int4*)&ind_lds[t & 1][g*8];
        *(int4*)&idv[4] = *(const int4*)&ind_lds[t & 1][g*8 + 4];
        #pragma unroll
        for (int kt = 0; kt < 4; ++kt) {
            const int tgt = k0w + (kt << 4) + lc;
            half8v bf;
            #pragma unroll
            for (int j = 0; j < 8; ++j) bf[j] = (idv[j] == tgt) ? (_Float16)1.0f : (_Float16)0.0f;
            #pragma unroll
            for (int ci = 0; ci < 4; ++ci)
                acc[ci][kt] = __builtin_amdgcn_mfma_f32_16x16x32_f16(ah[ci], bf, acc[ci][kt], 0, 0, 0);
        }
        if (t < 31) {
            half4v h;
            #pragma unroll
            for (int i = 0; i < 4; ++i) h[i] = (_Float16)(((const float*)&nxt)[i]);
            *(half4v*)(&xsm[(t+1) & 1][0] + wb_hi) = h;
            if (tid < 8) *(int4*)&ind_lds[(t+1) & 1][tid*4] = niv;
        }
    }
    __syncthreads();

    float* ps = p_sum + (size_t)wg * (CDIM*KCODES);
    #pragma unroll
    for (int ci = 0; ci < 4; ++ci)
        #pragma unroll
        for (int kt = 0; kt < 4; ++kt)
            #pragma unroll
            for (int rr = 0; rr < 4; ++rr)
                ps[((ci << 4) + (g << 2) + rr)*KCODES + k0w + (kt << 4) + lc] = acc[ci][kt][rr];
    float* pc = p_cnt + wg * KCODES;
    for (int i = tid; i < KCODES; i += 512) pc[i] = s_cnt[i];
}

// ---------------------------------------------------------------- reduce stage 1: 256 -> 8 partials
__global__ __launch_bounds__(256) void k_reduce1(const float* __restrict__ p_sum,
    const float* __restrict__ p_cnt, float* __restrict__ partial8,
    float* __restrict__ cnt8, int wsl)
{
    const int ic = blockIdx.x & 31, ws = blockIdx.x >> 5;
    const int i4 = ic*1024 + threadIdx.x*4;
    const float* base = p_sum + (size_t)ws*wsl*(CDIM*KCODES) + i4;
    float4 s = make_float4(0.f, 0.f, 0.f, 0.f);
    for (int w = 0; w < wsl; ++w) {
        const float4 v = *(const float4*)(base + (size_t)w*(CDIM*KCODES));
        s.x += v.x; s.y += v.y; s.z += v.z; s.w += v.w;
    }
    *(float4*)(partial8 + ws*(CDIM*KCODES) + i4) = s;
    if (ic == 0) {
        for (int k = threadIdx.x; k < KCODES; k += 256) {
            float c = 0.f;
            for (int w = 0; w < wsl; ++w) c += p_cnt[(ws*wsl + w)*KCODES + k];
            cnt8[ws*KCODES + k] = c;
        }
    }
}

// ---------------------------------------------------------------- final: fused reduce2 + scalars + emb outputs
__global__ __launch_bounds__(512) void k_final(const float* __restrict__ partial8,
    const float* __restrict__ cnt8, const float* __restrict__ csz,
    const float* __restrict__ eavg, const float* __restrict__ diff_acc,
    float* __restrict__ out)
{
    __shared__ float red[512];
    __shared__ float cs_lds[512];
    const int k = threadIdx.x;
    float c = 0.f;
    #pragma unroll
    for (int p = 0; p < 8; ++p) c += cnt8[p*KCODES + k];
    const float ncs = csz[k]*0.99f + 0.01f*c;
    if (blockIdx.x == 0) out[OFF_CSZ + k] = ncs;
    red[k] = ncs;
    __syncthreads();
    for (int s = 256; s > 0; s >>= 1) { if (k < s) red[k] += red[k+s]; __syncthreads(); }
    const float n = red[0];
    cs_lds[k] = (ncs + 1e-5f) / (n + 0.00512f) * n;
    if (blockIdx.x == 0 && k == 0) out[OFF_DIFF] = diff_acc[0] * (1.f/16777216.f);
    __syncthreads();
    if (k < 256) {
        const int i = (blockIdx.x*256 + k)*4;        // 32*256*4 = 32768
        float4 s4 = make_float4(0.f, 0.f, 0.f, 0.f);
        #pragma unroll
        for (int p = 0; p < 8; ++p) {
            const float4 v = *(const float4*)(partial8 + p*(CDIM*KCODES) + i);
            s4.x += v.x; s4.y += v.y; s4.z += v.z; s4.w += v.w;
        }
        const float4 ea = *(const float4*)(eavg + i);
        const float a0 = ea.x*0.99f + 0.01f*s4.x;
        const float a1 = ea.y*0.99f + 0.01f*s4.y;
        const float a2 = ea.z*0.99f + 0.01f*s4.z;
        const float a3 = ea.w*0.99f + 0.01f*s4.w;
        const int kb = i & (KCODES-1);
        out[OFF_AVG + i]     = a0;  out[OFF_AVG + i + 1] = a1;
        out[OFF_AVG + i + 2] = a2;  out[OFF_AVG + i + 3] = a3;
        out[OFF_EMB + i]     = a0 / cs_lds[kb];
        out[OFF_EMB + i + 1] = a1 / cs_lds[kb + 1];
        out[OFF_EMB + i + 2] = a2 / cs_lds[kb + 2];
        out[OFF_EMB + i + 3] = a3 / cs_lds[kb + 3];
    }
}

// ----------------------------------------------------------------
extern "C" void kernel_launch(void* const* d_in, const int* in_sizes, int n_in,
                              void* d_out, int out_size, void* d_ws, size_t ws_size,
                              hipStream_t stream)
{
    const float* in   = (const float*)d_in[0];
    const float* emb  = (const float*)d_in[1];
    const float* csz  = (const float*)d_in[2];
    const float* eavg = (const float*)d_in[3];
    float* out = (float*)d_out;
    char* ws = (char*)d_ws;

    // workspace layout (16B-aligned)
    int*      ind      = (int*)(ws + 2048);               //   1 MiB
    float*    diff_acc = (float*)(ws + 1050624);          //   4 B
    unsigned* nflag    = (unsigned*)(ws + 1050640);       //   4 B
    int*      flaglist = (int*)(ws + 1050656);            //   256 KiB
    const size_t off_part = 1447968;
    const int swgs = STATS_WGS;                            // 256 proven (r16: 512 cost +24us partial traffic)
    float* p_sum    = (float*)(ws + off_part);
    float* p_cnt    = (float*)(ws + off_part + (size_t)swgs*(CDIM*KCODES)*4);
    float* partial8 = (float*)(ws + off_part + (size_t)swgs*133120);
    float* cnt8     = (float*)(ws + off_part + (size_t)swgs*133120 + 1048576);

    hipMemsetAsync(ws + 1050624, 0, 32, stream);          // diff_acc + nflag

    hipLaunchKernelGGL(k_main,    dim3(256),        dim3(512), 0, stream, in, emb, out, ind, diff_acc, nflag, flaglist);
    hipLaunchKernelGGL(k_refine,  dim3(256),        dim3(256), 0, stream, in, emb, nflag, flaglist, ind, out);
    hipLaunchKernelGGL(k_tail,    dim3(STATS_WGS + 8192), dim3(512), 0, stream, in, emb, ind, p_sum, p_cnt, out);
    hipLaunchKernelGGL(k_reduce1, dim3(256),        dim3(256), 0, stream, p_sum, p_cnt, partial8, cnt8, swgs >> 3);
    hipLaunchKernelGGL(k_final,   dim3(32),         dim3(512), 0, stream, partial8, cnt8, csz, eavg, diff_acc, out);
}

// Round 18
// 194.077 us; speedup vs baseline: 1.5659x; 1.0157x over previous
//
#include <hip/hip_runtime.h>
#include <cstdint>
#include <cstddef>

typedef _Float16 half4v __attribute__((ext_vector_type(4)));
typedef _Float16 half8v __attribute__((ext_vector_type(8)));
typedef float    f32x4  __attribute__((ext_vector_type(4)));

#define N_PTS   262144
#define CDIM    64
#define KCODES  512
#define TAUA    5e-3f          // acc-units; true-dist gap = 2*acc gap -> 1e-2 (r10 proven)
#define FLAG_CAP 65536u
#define STATS_WGS 256

// output offsets (floats): out, diff, embedding_ind, new_embedding, new_cluster_size, new_embedding_avg
#define OFF_DIFF 16777216u
#define OFF_IND  16777217u
#define OFF_EMB  17039361u
#define OFF_CSZ  17072129u
#define OFF_AVG  17072641u

// ---------------------------------------------------------------- main: MFMA f16x2-split distances + argmin
// acc = ee/2 + (-x)*e  ->  dist = 2*acc + xx  (argmin equivalent in acc units)
// r10-proven structure (102us floor over 6 experiments). r18: OFF_IND writes moved to k_tail.
__global__ __launch_bounds__(512) void k_main(
    const float* __restrict__ in, const float* __restrict__ emb,
    float* __restrict__ out,
    int* __restrict__ ind_buf, float* __restrict__ diff_acc,
    unsigned* __restrict__ nflag, int* __restrict__ flaglist)
{
    // LDS: B_hi [64KiB] | B_lo [64KiB] | ee2 [2KiB]   (swizzled: byte ^= (col&7)<<4)
    __shared__ __align__(16) char bsm[133120];
    float* ee2_lds = (float*)(bsm + 131072);
    const int tid = threadIdx.x;

    // ---- stage codebook: fp32 -> f16 hi/lo, swizzled; ee2 computed inline ----
    {
        const int col = tid;                 // 512 threads = 512 cols
        const int xr  = (col & 7) << 4;
        float s = 0.f;
        #pragma unroll
        for (int c0 = 0; c0 < CDIM; c0 += 4) {
            float v[4];
            #pragma unroll
            for (int i = 0; i < 4; ++i) v[i] = emb[(c0 + i)*KCODES + col];
            half4v h, lo;
            #pragma unroll
            for (int i = 0; i < 4; ++i) {
                s = fmaf(v[i], v[i], s);
                _Float16 hh = (_Float16)v[i];
                h[i]  = hh;
                lo[i] = (_Float16)(v[i] - (float)hh);
            }
            const int wb = col*128 + ((c0*2) ^ xr);
            *(half4v*)(bsm + wb)         = h;
            *(half4v*)(bsm + 65536 + wb) = lo;
        }
        ee2_lds[col] = 0.5f * s;
    }
    __syncthreads();

    const int w  = tid >> 6, l = tid & 63;
    const int g  = l >> 4,  lc = l & 15;

    for (int r = 0; r < 2; ++r) {
        const int pbase = (blockIdx.x << 10) + (r << 9) + (w << 6);  // 64 points/wave
        const int b     = pbase >> 12;
        const float* inb = in + ((size_t)b << 18) + ((pbase & 4095) + lc);

        // ---- A fragments: negated x, exact f16 split; xx accumulated on the fly ----
        half8v ah[4][2], al[4][2];
        float xs = 0.f;
        #pragma unroll
        for (int t = 0; t < 4; ++t)
            #pragma unroll
            for (int s = 0; s < 2; ++s)
                #pragma unroll
                for (int j = 0; j < 8; ++j) {
                    const int c = s*32 + g*8 + j;
                    const float x = inb[(size_t)c*4096 + t*16];
                    xs = fmaf(x, x, xs);
                    const float xf = -x;
                    const _Float16 hh = (_Float16)xf;
                    ah[t][s][j] = hh;
                    al[t][s][j] = (_Float16)(xf - (float)hh);
                }

        float d1[4][4], d2[4][4]; int k1[4][4];
        #pragma unroll
        for (int t = 0; t < 4; ++t)
            #pragma unroll
            for (int rr = 0; rr < 4; ++rr) { d1[t][rr] = 3.4e38f; d2[t][rr] = 3.4e38f; k1[t][rr] = 0; }

        for (int ct = 0; ct < 32; ++ct) {
            const int col  = (ct << 4) + lc;
            const float sd = ee2_lds[col];
            const int rb   = col*128 + ((g*16) ^ ((col & 7) << 4));
            half8v bh0 = *(const half8v*)(bsm + rb);
            half8v bh1 = *(const half8v*)(bsm + (rb ^ 64));
            half8v bl0 = *(const half8v*)(bsm + 65536 + rb);
            half8v bl1 = *(const half8v*)(bsm + 65536 + (rb ^ 64));

            #pragma unroll
            for (int t = 0; t < 4; ++t) {
                // two independent 3-deep chains (K-halves s=0 / s=1)
                f32x4 acc0 = {sd, sd, sd, sd};
                f32x4 acc1 = {0.f, 0.f, 0.f, 0.f};
                acc0 = __builtin_amdgcn_mfma_f32_16x16x32_f16(al[t][0], bh0, acc0, 0, 0, 0);
                acc1 = __builtin_amdgcn_mfma_f32_16x16x32_f16(al[t][1], bh1, acc1, 0, 0, 0);
                acc0 = __builtin_amdgcn_mfma_f32_16x16x32_f16(ah[t][0], bl0, acc0, 0, 0, 0);
                acc1 = __builtin_amdgcn_mfma_f32_16x16x32_f16(ah[t][1], bl1, acc1, 0, 0, 0);
                acc0 = __builtin_amdgcn_mfma_f32_16x16x32_f16(ah[t][0], bh0, acc0, 0, 0, 0);
                acc1 = __builtin_amdgcn_mfma_f32_16x16x32_f16(ah[t][1], bh1, acc1, 0, 0, 0);
                #pragma unroll
                for (int rr = 0; rr < 4; ++rr) {
                    const float d = acc0[rr] + acc1[rr];
                    const bool cc = d < d1[t][rr];
                    d2[t][rr] = fminf(d2[t][rr], fmaxf(d, d1[t][rr]));
                    d1[t][rr] = fminf(d1[t][rr], d);
                    k1[t][rr] = cc ? col : k1[t][rr];
                }
            }
        }

        // ---- cross-lane best-2 merge over the 16 col-lanes ----
        #pragma unroll
        for (int m = 1; m <= 8; m <<= 1) {
            #pragma unroll
            for (int t = 0; t < 4; ++t)
                #pragma unroll
                for (int rr = 0; rr < 4; ++rr) {
                    const float od1 = __shfl_xor(d1[t][rr], m);
                    const int   ok1 = __shfl_xor(k1[t][rr], m);
                    const float od2 = __shfl_xor(d2[t][rr], m);
                    const float nd2 = fminf(fmaxf(d1[t][rr], od1), fminf(d2[t][rr], od2));
                    const bool take = (od1 < d1[t][rr]) || (od1 == d1[t][rr] && ok1 < k1[t][rr]);
                    d1[t][rr] = take ? od1 : d1[t][rr];
                    k1[t][rr] = take ? ok1 : k1[t][rr];
                    d2[t][rr] = nd2;
                }
        }

        // ---- outputs: indices (ind_buf only; OFF_IND written by k_tail), flags, diff partial ----
        float ds = 0.f;
        if (lc == 0) {
            #pragma unroll
            for (int t = 0; t < 4; ++t) {
                const int nb = pbase + t*16 + (g << 2);
                int4 iv = make_int4(k1[t][0], k1[t][1], k1[t][2], k1[t][3]);
                *(int4*)(ind_buf + nb) = iv;
                #pragma unroll
                for (int rr = 0; rr < 4; ++rr) {
                    ds += d1[t][rr];
                    if (d2[t][rr] - d1[t][rr] < TAUA) {
                        unsigned ix = atomicAdd(nflag, 1u);
                        if (ix < FLAG_CAP) flaglist[ix] = nb + rr;
                    }
                }
            }
        }
        #pragma unroll
        for (int m = 1; m < 64; m <<= 1) {
            ds += __shfl_xor(ds, m);
            xs += __shfl_xor(xs, m);
        }
        if (l == 0) atomicAdd(diff_acc, 2.f*ds + xs);
    }
}

// ---------------------------------------------------------------- f64 exact re-scan for near-ties
__global__ void k_refine(const float* __restrict__ in, const float* __restrict__ emb,
                         const unsigned* __restrict__ nflag, const int* __restrict__ flaglist,
                         int* __restrict__ ind_buf)
{
    const int gtid = blockIdx.x*blockDim.x + threadIdx.x;
    const int wid  = gtid >> 6;
    const int lane = threadIdx.x & 63;
    const int nw   = (gridDim.x * blockDim.x) >> 6;
    unsigned nf = *nflag; if (nf > FLAG_CAP) nf = FLAG_CAP;
    for (unsigned f = wid; f < nf; f += nw) {
        const int n = flaglist[f];
        const int b = n >> 12, hw = n & 4095;
        const float* xb = in + ((size_t)b << 18) + hw;
        const float* er = emb + lane*8;
        double dd[8] = {0,0,0,0,0,0,0,0};
        for (int c = 0; c < CDIM; ++c) {
            const double xv = (double)xb[(size_t)c << 12];   // wave-uniform
            #pragma unroll
            for (int j = 0; j < 8; ++j) {
                double t = xv - (double)er[c*KCODES + j];
                dd[j] = fma(t, t, dd[j]);
            }
        }
        double bd = 1e300; int bk = 0;
        #pragma unroll
        for (int j = 0; j < 8; ++j) {
            const int kk = lane*8 + j;
            if (dd[j] < bd) { bd = dd[j]; bk = kk; }
        }
        for (int off = 32; off; off >>= 1) {
            double od = __shfl_xor(bd, off);
            int    ok = __shfl_xor(bk, off);
            if (od < bd || (od == bd && ok < bk)) { bd = od; bk = ok; }
        }
        if (lane == 0) ind_buf[n] = bk;
    }
}

// ---------------------------------------------------------------- fused tail: stats (blocks 0..255) + quantize+indices (blocks 256..8447)
// stats: MFMA segment-sum, hi-only f16 (proven). quant: streaming gather-write + OFF_IND
// writes (post-refine ind_buf -> exact). Grid-partitioned for latency/BW overlap (r17: -12us).
__global__ __launch_bounds__(512) void k_tail(const float* __restrict__ in,
    const float* __restrict__ emb, const int* __restrict__ ind_buf,
    float* __restrict__ p_sum, float* __restrict__ p_cnt, float* __restrict__ out)
{
    __shared__ __align__(16) char xsm[2][CDIM*128];   // row c: [hi 32p | unused], byte ^= (c&7)<<4
    __shared__ int   ind_lds[2][32];
    __shared__ float s_cnt[KCODES];

    const int tid = threadIdx.x;

    if (blockIdx.x >= STATS_WGS) {
        // ---- quantize: out[b][c][hw] = emb[c][ind[b][hw]]; c==0 also writes OFF_IND ----
        const int gid = (blockIdx.x - STATS_WGS)*512 + tid;
        const int i  = gid << 2;
        const int hw = i & 4095;
        const int c  = (i >> 12) & 63;
        const int b  = i >> 18;
        const int n  = (b << 12) + hw;
        const int4 iv = *(const int4*)(ind_buf + n);
        const float* er = emb + (c << 9);
        float4 o = make_float4(er[iv.x], er[iv.y], er[iv.z], er[iv.w]);
        *(float4*)(out + i) = o;
        if (c == 0) {
            out[OFF_IND + n]     = (float)iv.x;
            out[OFF_IND + n + 1] = (float)iv.y;
            out[OFF_IND + n + 2] = (float)iv.z;
            out[OFF_IND + n + 3] = (float)iv.w;
        }
        return;
    }

    // ---- stats body (r10-proven) ----
    const int wg  = blockIdx.x;
    const int n0  = wg << 10;                 // 1024 points, all same batch b
    const int b   = n0 >> 12;
    const float* inb = in + ((size_t)b << 18) + (n0 & 4095);

    for (int i = tid; i < KCODES; i += 512) s_cnt[i] = 0.f;

    const int sc  = tid >> 3;                 // staging: channel 0..63
    const int sp  = (tid & 7) << 2;           // 4-point slot
    const int sxr = (sc & 7) << 4;
    const int wb_hi = sc*128 + ((sp*2) ^ sxr);

    const int w  = tid >> 6, l = tid & 63;
    const int g  = l >> 4,  lc = l & 15;
    const int k0w = w << 6;                   // wave's 64-code band

    f32x4 acc[4][4];
    #pragma unroll
    for (int ci = 0; ci < 4; ++ci)
        #pragma unroll
        for (int kt = 0; kt < 4; ++kt) acc[ci][kt] = (f32x4){0.f, 0.f, 0.f, 0.f};

    // prologue: stage chunk 0
    {
        const float4 xv = *(const float4*)(inb + (size_t)sc*4096 + sp);
        half4v h;
        #pragma unroll
        for (int i = 0; i < 4; ++i) h[i] = (_Float16)(((const float*)&xv)[i]);
        *(half4v*)(&xsm[0][0] + wb_hi) = h;
        if (tid < 8) *(int4*)&ind_lds[0][tid*4] = *(const int4*)(ind_buf + n0 + tid*4);
    }

    for (int t = 0; t < 32; ++t) {
        __syncthreads();
        float4 nxt; int4 niv;
        if (t < 31) {
            nxt = *(const float4*)(inb + (size_t)sc*4096 + (t+1)*32 + sp);
            if (tid < 8) niv = *(const int4*)(ind_buf + n0 + (t+1)*32 + tid*4);
        }
        if (tid < 32) atomicAdd(&s_cnt[ind_lds[t & 1][tid]], 1.f);

        const char* xb = &xsm[t & 1][0];
        half8v ah[4];
        #pragma unroll
        for (int ci = 0; ci < 4; ++ci) {
            const int c  = (ci << 4) + lc;
            const int xr = (c & 7) << 4;
            ah[ci] = *(const half8v*)(xb + c*128 + ((g*16) ^ xr));
        }
        int idv[8];
        *(int4*)&idv[0] = *(const int4*)&ind_lds[t & 1][g*8];
        *(int4*)&idv[4] = *(const int4*)&ind_lds[t & 1][g*8 + 4];
        #pragma unroll
        for (int kt = 0; kt < 4; ++kt) {
            const int tgt = k0w + (kt << 4) + lc;
            half8v bf;
            #pragma unroll
            for (int j = 0; j < 8; ++j) bf[j] = (idv[j] == tgt) ? (_Float16)1.0f : (_Float16)0.0f;
            #pragma unroll
            for (int ci = 0; ci < 4; ++ci)
                acc[ci][kt] = __builtin_amdgcn_mfma_f32_16x16x32_f16(ah[ci], bf, acc[ci][kt], 0, 0, 0);
        }
        if (t < 31) {
            half4v h;
            #pragma unroll
            for (int i = 0; i < 4; ++i) h[i] = (_Float16)(((const float*)&nxt)[i]);
            *(half4v*)(&xsm[(t+1) & 1][0] + wb_hi) = h;
            if (tid < 8) *(int4*)&ind_lds[(t+1) & 1][tid*4] = niv;
        }
    }
    __syncthreads();

    float* ps = p_sum + (size_t)wg * (CDIM*KCODES);
    #pragma unroll
    for (int ci = 0; ci < 4; ++ci)
        #pragma unroll
        for (int kt = 0; kt < 4; ++kt)
            #pragma unroll
            for (int rr = 0; rr < 4; ++rr)
                ps[((ci << 4) + (g << 2) + rr)*KCODES + k0w + (kt << 4) + lc] = acc[ci][kt][rr];
    float* pc = p_cnt + wg * KCODES;
    for (int i = tid; i < KCODES; i += 512) pc[i] = s_cnt[i];
}

// ---------------------------------------------------------------- last: fused partial-reduce + scalars + emb outputs
// 32 blocks x 512. Each block: redundant cnt reduction (512KiB) -> cs[]; block 0 writes CSZ+DIFF;
// then reduces its 1/32 slice of p_sum (256 partials, coalesced float4 columns) -> AVG + EMB.
__global__ __launch_bounds__(512) void k_last(const float* __restrict__ p_sum,
    const float* __restrict__ p_cnt, const float* __restrict__ csz,
    const float* __restrict__ eavg, const float* __restrict__ diff_acc,
    float* __restrict__ out)
{
    __shared__ float red[512];
    __shared__ float cs_lds[512];
    const int k = threadIdx.x;
    float c = 0.f;
    for (int w = 0; w < STATS_WGS; ++w) c += p_cnt[w*KCODES + k];
    const float ncs = csz[k]*0.99f + 0.01f*c;
    if (blockIdx.x == 0) out[OFF_CSZ + k] = ncs;
    red[k] = ncs;
    __syncthreads();
    for (int s = 256; s > 0; s >>= 1) { if (k < s) red[k] += red[k+s]; __syncthreads(); }
    const float n = red[0];
    cs_lds[k] = (ncs + 1e-5f) / (n + 0.00512f) * n;
    if (blockIdx.x == 0 && k == 0) out[OFF_DIFF] = diff_acc[0] * (1.f/16777216.f);
    __syncthreads();
    if (k < 256) {
        const int i = blockIdx.x*1024 + k*4;         // 32 blocks x 1024 = 32768
        float4 s4 = make_float4(0.f, 0.f, 0.f, 0.f);
        for (int w = 0; w < STATS_WGS; ++w) {
            const float4 v = *(const float4*)(p_sum + (size_t)w*(CDIM*KCODES) + i);
            s4.x += v.x; s4.y += v.y; s4.z += v.z; s4.w += v.w;
        }
        const float4 ea = *(const float4*)(eavg + i);
        const float a0 = ea.x*0.99f + 0.01f*s4.x;
        const float a1 = ea.y*0.99f + 0.01f*s4.y;
        const float a2 = ea.z*0.99f + 0.01f*s4.z;
        const float a3 = ea.w*0.99f + 0.01f*s4.w;
        const int kb = i & (KCODES-1);
        out[OFF_AVG + i]     = a0;  out[OFF_AVG + i + 1] = a1;
        out[OFF_AVG + i + 2] = a2;  out[OFF_AVG + i + 3] = a3;
        out[OFF_EMB + i]     = a0 / cs_lds[kb];
        out[OFF_EMB + i + 1] = a1 / cs_lds[kb + 1];
        out[OFF_EMB + i + 2] = a2 / cs_lds[kb + 2];
        out[OFF_EMB + i + 3] = a3 / cs_lds[kb + 3];
    }
}

// ----------------------------------------------------------------
extern "C" void kernel_launch(void* const* d_in, const int* in_sizes, int n_in,
                              void* d_out, int out_size, void* d_ws, size_t ws_size,
                              hipStream_t stream)
{
    const float* in   = (const float*)d_in[0];
    const float* emb  = (const float*)d_in[1];
    const float* csz  = (const float*)d_in[2];
    const float* eavg = (const float*)d_in[3];
    float* out = (float*)d_out;
    char* ws = (char*)d_ws;

    // workspace layout (16B-aligned)
    int*      ind      = (int*)(ws + 2048);               //   1 MiB
    float*    diff_acc = (float*)(ws + 1050624);          //   4 B
    unsigned* nflag    = (unsigned*)(ws + 1050640);       //   4 B
    int*      flaglist = (int*)(ws + 1050656);            //   256 KiB
    const size_t off_part = 1447968;
    const int swgs = STATS_WGS;                            // 256 proven (r16: 512 cost +24us partial traffic)
    float* p_sum = (float*)(ws + off_part);
    float* p_cnt = (float*)(ws + off_part + (size_t)swgs*(CDIM*KCODES)*4);

    hipMemsetAsync(ws + 1050624, 0, 32, stream);          // diff_acc + nflag

    hipLaunchKernelGGL(k_main,   dim3(256),              dim3(512), 0, stream, in, emb, out, ind, diff_acc, nflag, flaglist);
    hipLaunchKernelGGL(k_refine, dim3(256),              dim3(256), 0, stream, in, emb, nflag, flaglist, ind);
    hipLaunchKernelGGL(k_tail,   dim3(STATS_WGS + 8192), dim3(512), 0, stream, in, emb, ind, p_sum, p_cnt, out);
    hipLaunchKernelGGL(k_last,   dim3(32),               dim3(512), 0, stream, p_sum, p_cnt, csz, eavg, diff_acc, out);
}

// Round 19
// 185.412 us; speedup vs baseline: 1.6391x; 1.0467x over previous
//
#include <hip/hip_runtime.h>
#include <cstdint>
#include <cstddef>

typedef _Float16 half4v __attribute__((ext_vector_type(4)));
typedef _Float16 half8v __attribute__((ext_vector_type(8)));
typedef float    f32x4  __attribute__((ext_vector_type(4)));

#define N_PTS   262144
#define CDIM    64
#define KCODES  512
#define TAUA    5e-3f          // acc-units; true-dist gap = 2*acc gap -> 1e-2 (r10 proven)
#define FLAG_CAP 65536u
#define STATS_WGS 256

// output offsets (floats): out, diff, embedding_ind, new_embedding, new_cluster_size, new_embedding_avg
#define OFF_DIFF 16777216u
#define OFF_IND  16777217u
#define OFF_EMB  17039361u
#define OFF_CSZ  17072129u
#define OFF_AVG  17072641u

// ---------------------------------------------------------------- main: MFMA f16x2-split distances + argmin
// acc = ee/2 + (-x)*e  ->  dist = 2*acc + xx  (argmin equivalent in acc units)
// r10-proven structure (100us floor over 6 experiments).
__global__ __launch_bounds__(512) void k_main(
    const float* __restrict__ in, const float* __restrict__ emb,
    float* __restrict__ out,
    int* __restrict__ ind_buf, float* __restrict__ diff_acc,
    unsigned* __restrict__ nflag, int* __restrict__ flaglist)
{
    // LDS: B_hi [64KiB] | B_lo [64KiB] | ee2 [2KiB]   (swizzled: byte ^= (col&7)<<4)
    __shared__ __align__(16) char bsm[133120];
    float* ee2_lds = (float*)(bsm + 131072);
    const int tid = threadIdx.x;

    // ---- stage codebook: fp32 -> f16 hi/lo, swizzled; ee2 computed inline ----
    {
        const int col = tid;                 // 512 threads = 512 cols
        const int xr  = (col & 7) << 4;
        float s = 0.f;
        #pragma unroll
        for (int c0 = 0; c0 < CDIM; c0 += 4) {
            float v[4];
            #pragma unroll
            for (int i = 0; i < 4; ++i) v[i] = emb[(c0 + i)*KCODES + col];
            half4v h, lo;
            #pragma unroll
            for (int i = 0; i < 4; ++i) {
                s = fmaf(v[i], v[i], s);
                _Float16 hh = (_Float16)v[i];
                h[i]  = hh;
                lo[i] = (_Float16)(v[i] - (float)hh);
            }
            const int wb = col*128 + ((c0*2) ^ xr);
            *(half4v*)(bsm + wb)         = h;
            *(half4v*)(bsm + 65536 + wb) = lo;
        }
        ee2_lds[col] = 0.5f * s;
    }
    __syncthreads();

    const int w  = tid >> 6, l = tid & 63;
    const int g  = l >> 4,  lc = l & 15;

    for (int r = 0; r < 2; ++r) {
        const int pbase = (blockIdx.x << 10) + (r << 9) + (w << 6);  // 64 points/wave
        const int b     = pbase >> 12;
        const float* inb = in + ((size_t)b << 18) + ((pbase & 4095) + lc);

        // ---- A fragments: negated x, exact f16 split; xx accumulated on the fly ----
        half8v ah[4][2], al[4][2];
        float xs = 0.f;
        #pragma unroll
        for (int t = 0; t < 4; ++t)
            #pragma unroll
            for (int s = 0; s < 2; ++s)
                #pragma unroll
                for (int j = 0; j < 8; ++j) {
                    const int c = s*32 + g*8 + j;
                    const float x = inb[(size_t)c*4096 + t*16];
                    xs = fmaf(x, x, xs);
                    const float xf = -x;
                    const _Float16 hh = (_Float16)xf;
                    ah[t][s][j] = hh;
                    al[t][s][j] = (_Float16)(xf - (float)hh);
                }

        float d1[4][4], d2[4][4]; int k1[4][4];
        #pragma unroll
        for (int t = 0; t < 4; ++t)
            #pragma unroll
            for (int rr = 0; rr < 4; ++rr) { d1[t][rr] = 3.4e38f; d2[t][rr] = 3.4e38f; k1[t][rr] = 0; }

        for (int ct = 0; ct < 32; ++ct) {
            const int col  = (ct << 4) + lc;
            const float sd = ee2_lds[col];
            const int rb   = col*128 + ((g*16) ^ ((col & 7) << 4));
            half8v bh0 = *(const half8v*)(bsm + rb);
            half8v bh1 = *(const half8v*)(bsm + (rb ^ 64));
            half8v bl0 = *(const half8v*)(bsm + 65536 + rb);
            half8v bl1 = *(const half8v*)(bsm + 65536 + (rb ^ 64));

            #pragma unroll
            for (int t = 0; t < 4; ++t) {
                // two independent 3-deep chains (K-halves s=0 / s=1)
                f32x4 acc0 = {sd, sd, sd, sd};
                f32x4 acc1 = {0.f, 0.f, 0.f, 0.f};
                acc0 = __builtin_amdgcn_mfma_f32_16x16x32_f16(al[t][0], bh0, acc0, 0, 0, 0);
                acc1 = __builtin_amdgcn_mfma_f32_16x16x32_f16(al[t][1], bh1, acc1, 0, 0, 0);
                acc0 = __builtin_amdgcn_mfma_f32_16x16x32_f16(ah[t][0], bl0, acc0, 0, 0, 0);
                acc1 = __builtin_amdgcn_mfma_f32_16x16x32_f16(ah[t][1], bl1, acc1, 0, 0, 0);
                acc0 = __builtin_amdgcn_mfma_f32_16x16x32_f16(ah[t][0], bh0, acc0, 0, 0, 0);
                acc1 = __builtin_amdgcn_mfma_f32_16x16x32_f16(ah[t][1], bh1, acc1, 0, 0, 0);
                #pragma unroll
                for (int rr = 0; rr < 4; ++rr) {
                    const float d = acc0[rr] + acc1[rr];
                    const bool cc = d < d1[t][rr];
                    d2[t][rr] = fminf(d2[t][rr], fmaxf(d, d1[t][rr]));
                    d1[t][rr] = fminf(d1[t][rr], d);
                    k1[t][rr] = cc ? col : k1[t][rr];
                }
            }
        }

        // ---- cross-lane best-2 merge over the 16 col-lanes ----
        #pragma unroll
        for (int m = 1; m <= 8; m <<= 1) {
            #pragma unroll
            for (int t = 0; t < 4; ++t)
                #pragma unroll
                for (int rr = 0; rr < 4; ++rr) {
                    const float od1 = __shfl_xor(d1[t][rr], m);
                    const int   ok1 = __shfl_xor(k1[t][rr], m);
                    const float od2 = __shfl_xor(d2[t][rr], m);
                    const float nd2 = fminf(fmaxf(d1[t][rr], od1), fminf(d2[t][rr], od2));
                    const bool take = (od1 < d1[t][rr]) || (od1 == d1[t][rr] && ok1 < k1[t][rr]);
                    d1[t][rr] = take ? od1 : d1[t][rr];
                    k1[t][rr] = take ? ok1 : k1[t][rr];
                    d2[t][rr] = nd2;
                }
        }

        // ---- outputs: indices (ind_buf; OFF_IND written by k_tail), flags, diff partial ----
        float ds = 0.f;
        if (lc == 0) {
            #pragma unroll
            for (int t = 0; t < 4; ++t) {
                const int nb = pbase + t*16 + (g << 2);
                int4 iv = make_int4(k1[t][0], k1[t][1], k1[t][2], k1[t][3]);
                *(int4*)(ind_buf + nb) = iv;
                #pragma unroll
                for (int rr = 0; rr < 4; ++rr) {
                    ds += d1[t][rr];
                    if (d2[t][rr] - d1[t][rr] < TAUA) {
                        unsigned ix = atomicAdd(nflag, 1u);
                        if (ix < FLAG_CAP) flaglist[ix] = nb + rr;
                    }
                }
            }
        }
        #pragma unroll
        for (int m = 1; m < 64; m <<= 1) {
            ds += __shfl_xor(ds, m);
            xs += __shfl_xor(xs, m);
        }
        if (l == 0) atomicAdd(diff_acc, 2.f*ds + xs);
    }
}

// ---------------------------------------------------------------- f64 exact re-scan for near-ties
__global__ void k_refine(const float* __restrict__ in, const float* __restrict__ emb,
                         const unsigned* __restrict__ nflag, const int* __restrict__ flaglist,
                         int* __restrict__ ind_buf)
{
    const int gtid = blockIdx.x*blockDim.x + threadIdx.x;
    const int wid  = gtid >> 6;
    const int lane = threadIdx.x & 63;
    const int nw   = (gridDim.x * blockDim.x) >> 6;
    unsigned nf = *nflag; if (nf > FLAG_CAP) nf = FLAG_CAP;
    for (unsigned f = wid; f < nf; f += nw) {
        const int n = flaglist[f];
        const int b = n >> 12, hw = n & 4095;
        const float* xb = in + ((size_t)b << 18) + hw;
        const float* er = emb + lane*8;
        double dd[8] = {0,0,0,0,0,0,0,0};
        for (int c = 0; c < CDIM; ++c) {
            const double xv = (double)xb[(size_t)c << 12];   // wave-uniform
            #pragma unroll
            for (int j = 0; j < 8; ++j) {
                double t = xv - (double)er[c*KCODES + j];
                dd[j] = fma(t, t, dd[j]);
            }
        }
        double bd = 1e300; int bk = 0;
        #pragma unroll
        for (int j = 0; j < 8; ++j) {
            const int kk = lane*8 + j;
            if (dd[j] < bd) { bd = dd[j]; bk = kk; }
        }
        for (int off = 32; off; off >>= 1) {
            double od = __shfl_xor(bd, off);
            int    ok = __shfl_xor(bk, off);
            if (od < bd || (od == bd && ok < bk)) { bd = od; bk = ok; }
        }
        if (lane == 0) ind_buf[n] = bk;
    }
}

// ---------------------------------------------------------------- fused tail: stats (blocks 0..255) + quantize+indices (blocks 256..8447)
// stats: MFMA segment-sum, hi-only f16 (proven); counts go straight to cnt_tot via atomics
// (saves 256-copy p_cnt round-trip). quant: streaming gather-write + OFF_IND (post-refine -> exact).
__global__ __launch_bounds__(512) void k_tail(const float* __restrict__ in,
    const float* __restrict__ emb, const int* __restrict__ ind_buf,
    float* __restrict__ p_sum, float* __restrict__ cnt_tot, float* __restrict__ out)
{
    __shared__ __align__(16) char xsm[2][CDIM*128];   // row c: [hi 32p | unused], byte ^= (c&7)<<4
    __shared__ int   ind_lds[2][32];
    __shared__ float s_cnt[KCODES];

    const int tid = threadIdx.x;

    if (blockIdx.x >= STATS_WGS) {
        // ---- quantize: out[b][c][hw] = emb[c][ind[b][hw]]; c==0 also writes OFF_IND ----
        const int gid = (blockIdx.x - STATS_WGS)*512 + tid;
        const int i  = gid << 2;
        const int hw = i & 4095;
        const int c  = (i >> 12) & 63;
        const int b  = i >> 18;
        const int n  = (b << 12) + hw;
        const int4 iv = *(const int4*)(ind_buf + n);
        const float* er = emb + (c << 9);
        float4 o = make_float4(er[iv.x], er[iv.y], er[iv.z], er[iv.w]);
        *(float4*)(out + i) = o;
        if (c == 0) {
            out[OFF_IND + n]     = (float)iv.x;
            out[OFF_IND + n + 1] = (float)iv.y;
            out[OFF_IND + n + 2] = (float)iv.z;
            out[OFF_IND + n + 3] = (float)iv.w;
        }
        return;
    }

    // ---- stats body (r10-proven) ----
    const int wg  = blockIdx.x;
    const int n0  = wg << 10;                 // 1024 points, all same batch b
    const int b   = n0 >> 12;
    const float* inb = in + ((size_t)b << 18) + (n0 & 4095);

    for (int i = tid; i < KCODES; i += 512) s_cnt[i] = 0.f;

    const int sc  = tid >> 3;                 // staging: channel 0..63
    const int sp  = (tid & 7) << 2;           // 4-point slot
    const int sxr = (sc & 7) << 4;
    const int wb_hi = sc*128 + ((sp*2) ^ sxr);

    const int w  = tid >> 6, l = tid & 63;
    const int g  = l >> 4,  lc = l & 15;
    const int k0w = w << 6;                   // wave's 64-code band

    f32x4 acc[4][4];
    #pragma unroll
    for (int ci = 0; ci < 4; ++ci)
        #pragma unroll
        for (int kt = 0; kt < 4; ++kt) acc[ci][kt] = (f32x4){0.f, 0.f, 0.f, 0.f};

    // prologue: stage chunk 0
    {
        const float4 xv = *(const float4*)(inb + (size_t)sc*4096 + sp);
        half4v h;
        #pragma unroll
        for (int i = 0; i < 4; ++i) h[i] = (_Float16)(((const float*)&xv)[i]);
        *(half4v*)(&xsm[0][0] + wb_hi) = h;
        if (tid < 8) *(int4*)&ind_lds[0][tid*4] = *(const int4*)(ind_buf + n0 + tid*4);
    }

    for (int t = 0; t < 32; ++t) {
        __syncthreads();
        float4 nxt; int4 niv;
        if (t < 31) {
            nxt = *(const float4*)(inb + (size_t)sc*4096 + (t+1)*32 + sp);
            if (tid < 8) niv = *(const int4*)(ind_buf + n0 + (t+1)*32 + tid*4);
        }
        if (tid < 32) atomicAdd(&s_cnt[ind_lds[t & 1][tid]], 1.f);

        const char* xb = &xsm[t & 1][0];
        half8v ah[4];
        #pragma unroll
        for (int ci = 0; ci < 4; ++ci) {
            const int c  = (ci << 4) + lc;
            const int xr = (c & 7) << 4;
            ah[ci] = *(const half8v*)(xb + c*128 + ((g*16) ^ xr));
        }
        int idv[8];
        *(int4*)&idv[0] = *(const int4*)&ind_lds[t & 1][g*8];
        *(int4*)&idv[4] = *(const int4*)&ind_lds[t & 1][g*8 + 4];
        #pragma unroll
        for (int kt = 0; kt < 4; ++kt) {
            const int tgt = k0w + (kt << 4) + lc;
            half8v bf;
            #pragma unroll
            for (int j = 0; j < 8; ++j) bf[j] = (idv[j] == tgt) ? (_Float16)1.0f : (_Float16)0.0f;
            #pragma unroll
            for (int ci = 0; ci < 4; ++ci)
                acc[ci][kt] = __builtin_amdgcn_mfma_f32_16x16x32_f16(ah[ci], bf, acc[ci][kt], 0, 0, 0);
        }
        if (t < 31) {
            half4v h;
            #pragma unroll
            for (int i = 0; i < 4; ++i) h[i] = (_Float16)(((const float*)&nxt)[i]);
            *(half4v*)(&xsm[(t+1) & 1][0] + wb_hi) = h;
            if (tid < 8) *(int4*)&ind_lds[(t+1) & 1][tid*4] = niv;
        }
    }
    __syncthreads();

    float* ps = p_sum + (size_t)wg * (CDIM*KCODES);
    #pragma unroll
    for (int ci = 0; ci < 4; ++ci)
        #pragma unroll
        for (int kt = 0; kt < 4; ++kt)
            #pragma unroll
            for (int rr = 0; rr < 4; ++rr)
                ps[((ci << 4) + (g << 2) + rr)*KCODES + k0w + (kt << 4) + lc] = acc[ci][kt][rr];
    for (int i = tid; i < KCODES; i += 512) atomicAdd(&cnt_tot[i], s_cnt[i]);
}

// ---------------------------------------------------------------- last: scalars + emb outputs
// 256 blocks x 256 thr. Each block redundantly derives cs[] from cnt_tot (2KB), then reduces its
// 32-float4-column slice of p_sum (128KB) -> AVG + EMB. 8x more CUs than r18's 32-block version.
__global__ __launch_bounds__(256) void k_last(const float* __restrict__ p_sum,
    const float* __restrict__ cnt_tot, const float* __restrict__ csz,
    const float* __restrict__ eavg, const float* __restrict__ diff_acc,
    float* __restrict__ out)
{
    __shared__ float red[256];
    __shared__ float ncs_lds[512];
    __shared__ float cs_lds[512];
    const int tid = threadIdx.x;
    float part = 0.f;
    #pragma unroll
    for (int j = 0; j < 2; ++j) {
        const int k = j*256 + tid;
        const float ncs = csz[k]*0.99f + 0.01f*cnt_tot[k];
        ncs_lds[k] = ncs;
        part += ncs;
        if (blockIdx.x == 0) out[OFF_CSZ + k] = ncs;
    }
    red[tid] = part;
    __syncthreads();
    for (int s = 128; s > 0; s >>= 1) { if (tid < s) red[tid] += red[tid+s]; __syncthreads(); }
    const float n = red[0];
    #pragma unroll
    for (int j = 0; j < 2; ++j) {
        const int k = j*256 + tid;
        cs_lds[k] = (ncs_lds[k] + 1e-5f) / (n + 0.00512f) * n;
    }
    if (blockIdx.x == 0 && tid == 0) out[OFF_DIFF] = diff_acc[0] * (1.f/16777216.f);
    __syncthreads();
    if (tid < 32) {
        const int i = (blockIdx.x*32 + tid)*4;       // 256 blocks x 32 cols x 4 = 32768
        float4 s4 = make_float4(0.f, 0.f, 0.f, 0.f);
        for (int w = 0; w < STATS_WGS; ++w) {
            const float4 v = *(const float4*)(p_sum + (size_t)w*(CDIM*KCODES) + i);
            s4.x += v.x; s4.y += v.y; s4.z += v.z; s4.w += v.w;
        }
        const float4 ea = *(const float4*)(eavg + i);
        const float a0 = ea.x*0.99f + 0.01f*s4.x;
        const float a1 = ea.y*0.99f + 0.01f*s4.y;
        const float a2 = ea.z*0.99f + 0.01f*s4.z;
        const float a3 = ea.w*0.99f + 0.01f*s4.w;
        const int kb = i & (KCODES-1);
        out[OFF_AVG + i]     = a0;  out[OFF_AVG + i + 1] = a1;
        out[OFF_AVG + i + 2] = a2;  out[OFF_AVG + i + 3] = a3;
        out[OFF_EMB + i]     = a0 / cs_lds[kb];
        out[OFF_EMB + i + 1] = a1 / cs_lds[kb + 1];
        out[OFF_EMB + i + 2] = a2 / cs_lds[kb + 2];
        out[OFF_EMB + i + 3] = a3 / cs_lds[kb + 3];
    }
}

// ----------------------------------------------------------------
extern "C" void kernel_launch(void* const* d_in, const int* in_sizes, int n_in,
                              void* d_out, int out_size, void* d_ws, size_t ws_size,
                              hipStream_t stream)
{
    const float* in   = (const float*)d_in[0];
    const float* emb  = (const float*)d_in[1];
    const float* csz  = (const float*)d_in[2];
    const float* eavg = (const float*)d_in[3];
    float* out = (float*)d_out;
    char* ws = (char*)d_ws;

    // workspace layout (16B-aligned)
    int*      ind      = (int*)(ws + 2048);               //   1 MiB
    float*    diff_acc = (float*)(ws + 1050624);          //   4 B
    unsigned* nflag    = (unsigned*)(ws + 1050640);       //   4 B
    float*    cnt_tot  = (float*)(ws + 1050656);          //   2 KiB (zeroed each call)
    int*      flaglist = (int*)(ws + 1052704);            //   256 KiB
    const size_t off_part = 1447968;
    float* p_sum = (float*)(ws + off_part);               //   32 MiB (256 copies)

    hipMemsetAsync(ws + 1050624, 0, 2080, stream);        // diff_acc + nflag + cnt_tot

    hipLaunchKernelGGL(k_main,   dim3(256),              dim3(512), 0, stream, in, emb, out, ind, diff_acc, nflag, flaglist);
    hipLaunchKernelGGL(k_refine, dim3(256),              dim3(256), 0, stream, in, emb, nflag, flaglist, ind);
    hipLaunchKernelGGL(k_tail,   dim3(STATS_WGS + 8192), dim3(512), 0, stream, in, emb, ind, p_sum, cnt_tot, out);
    hipLaunchKernelGGL(k_last,   dim3(256),              dim3(256), 0, stream, p_sum, cnt_tot, csz, eavg, diff_acc, out);
}